// Round 1
// baseline (514.299 us; speedup 1.0000x reference)
//
#include <hip/hip_runtime.h>
#include <cstdint>
#include <cstddef>

#define Tt 2048
#define Hh 1024
#define Ff 3584
#define Ee 8
#define ROWS_CAP 5120

// ws layout (bytes)
#define OFF_CTRL   0u                         // 64 ints: [0:8) cnt, [8:16) fill, [16:25) off
#define OFF_TOKE   256u                       // 2T ints
#define OFF_TOKW   (256u + 16384u)            // 2T floats
#define OFF_ROWMAP (256u + 32768u)            // ROWS_CAP ints
#define OFF_ROWW   (256u + 32768u + 20480u)   // ROWS_CAP floats
#define OFF_XG     (1u << 20)                 // ROWS_CAP*H*2 = 10.5 MB
#define OFF_G      (12u << 20)                // ROWS_CAP*F*2 = 36.7 MB  (total ~47 MB)

typedef __attribute__((ext_vector_type(8))) short bf16x8;
typedef __attribute__((ext_vector_type(4))) float f32x4;

__device__ __forceinline__ unsigned short f2bf(float f) {
  unsigned int u = __float_as_uint(f);
  u += 0x7fffu + ((u >> 16) & 1u);
  return (unsigned short)(u >> 16);
}

__device__ __forceinline__ void gload_lds16(const void* g, void* l) {
  auto gp = (const __attribute__((address_space(1))) char*)(uintptr_t)g;
  auto lp = (__attribute__((address_space(3))) char*)(uintptr_t)l;
  __builtin_amdgcn_global_load_lds(gp, lp, 16, 0, 0);
}

// ---------------- router: fp32 logits, softmax, top-2, renorm ----------------
__global__ __launch_bounds__(256) void router_kernel(
    const float* __restrict__ x, const float* __restrict__ gw,
    float* __restrict__ logits_out, int* __restrict__ tok_e,
    float* __restrict__ tok_w, int* __restrict__ ctrl) {
  const int lane = threadIdx.x & 63;
  const int t = blockIdx.x * 4 + (threadIdx.x >> 6);
  const float4* xp = (const float4*)(x + (size_t)t * Hh + lane * 16);
  float4 x0 = xp[0], x1 = xp[1], x2 = xp[2], x3 = xp[3];
  float lg[Ee];
#pragma unroll
  for (int e = 0; e < Ee; ++e) {
    const float4* gp = (const float4*)(gw + e * Hh + lane * 16);
    float4 g0 = gp[0], g1 = gp[1], g2 = gp[2], g3 = gp[3];
    float s = x0.x*g0.x + x0.y*g0.y + x0.z*g0.z + x0.w*g0.w
            + x1.x*g1.x + x1.y*g1.y + x1.z*g1.z + x1.w*g1.w
            + x2.x*g2.x + x2.y*g2.y + x2.z*g2.z + x2.w*g2.w
            + x3.x*g3.x + x3.y*g3.y + x3.z*g3.z + x3.w*g3.w;
#pragma unroll
    for (int o = 32; o; o >>= 1) s += __shfl_xor(s, o);
    lg[e] = s;
  }
  if (lane == 0) {
    float m = lg[0];
#pragma unroll
    for (int e = 1; e < Ee; ++e) m = fmaxf(m, lg[e]);
    float p[Ee];
#pragma unroll
    for (int e = 0; e < Ee; ++e) p[e] = expf(lg[e] - m);
    int a0 = 0;
#pragma unroll
    for (int e = 1; e < Ee; ++e) if (p[e] > p[a0]) a0 = e;
    int a1 = (a0 == 0) ? 1 : 0;
#pragma unroll
    for (int e = 0; e < Ee; ++e) if (e != a0 && p[e] > p[a1]) a1 = e;
    float rs = p[a0] + p[a1];
    float w0 = p[a0] / rs, w1 = p[a1] / rs;
#pragma unroll
    for (int e = 0; e < Ee; ++e) logits_out[(size_t)t * Ee + e] = lg[e];
    tok_e[t * 2] = a0; tok_e[t * 2 + 1] = a1;
    tok_w[t * 2] = w0; tok_w[t * 2 + 1] = w1;
    atomicAdd(&ctrl[a0], 1); atomicAdd(&ctrl[a1], 1);
  }
}

// ------------- scan + assign rows (padded per-expert regions, BM=128) -------------
__global__ void scan_assign_kernel(int* ctrl, const int* __restrict__ tok_e,
                                   const float* __restrict__ tok_w,
                                   int* __restrict__ rowmap, float* __restrict__ roww) {
  if (threadIdx.x == 0) {
    int acc = 0;
    for (int e = 0; e < Ee; ++e) {
      ctrl[16 + e] = acc;
      acc += ((ctrl[e] + 127) >> 7) << 7;  // pad each expert to multiple of 128
    }
    ctrl[16 + Ee] = acc;
  }
  __syncthreads();
  for (int i = threadIdx.x; i < 2 * Tt; i += blockDim.x) {
    int e = tok_e[i];
    int pos = atomicAdd(&ctrl[8 + e], 1);
    int r = ctrl[16 + e] + pos;
    rowmap[r] = i >> 1;
    roww[r] = tok_w[i];
  }
  for (int i = threadIdx.x; i < Ee * 128; i += blockDim.x) {
    int e = i >> 7, pd = i & 127;
    int o = ctrl[16 + e], o1 = ctrl[16 + e + 1], c = ctrl[e];
    int r = o + c + pd;
    if (r < o1) { rowmap[r] = -1; roww[r] = 0.f; }
  }
}

// ---------------- gather x rows -> bf16 Xg (zeros for pad rows) ----------------
__global__ __launch_bounds__(128) void gather_kernel(
    const float* __restrict__ x, const int* __restrict__ ctrl,
    const int* __restrict__ rowmap, unsigned short* __restrict__ Xg) {
  int r = blockIdx.x;
  if (r >= ctrl[16 + Ee]) return;
  int t = rowmap[r];
  int j = threadIdx.x;
  uint4 v = make_uint4(0u, 0u, 0u, 0u);
  if (t >= 0) {
    const float4* xp = (const float4*)(x + (size_t)t * Hh + j * 8);
    float4 a = xp[0], b = xp[1];
    v.x = (unsigned)f2bf(a.x) | ((unsigned)f2bf(a.y) << 16);
    v.y = (unsigned)f2bf(a.z) | ((unsigned)f2bf(a.w) << 16);
    v.z = (unsigned)f2bf(b.x) | ((unsigned)f2bf(b.y) << 16);
    v.w = (unsigned)f2bf(b.z) | ((unsigned)f2bf(b.w) << 16);
  }
  *(uint4*)(Xg + (size_t)r * Hh + j * 8) = v;
}

// ---------- stage A: G = silu(Xg@w1) * (Xg@w3), BM=128 BN=128 BK=32 ----------
__global__ __launch_bounds__(256, 2) void ffn13_kernel(
    const unsigned short* __restrict__ Xg, const float* __restrict__ w1,
    const float* __restrict__ w3, const int* __restrict__ ctrl,
    unsigned short* __restrict__ G) {
  __shared__ unsigned short sA[128 * 32];   // [m][k], row = 64 B
  __shared__ unsigned short sB1[128 * 40];  // [n][k], stride 40 (pad 8)
  __shared__ unsigned short sB3[128 * 40];
  const int e = blockIdx.y >> 4, mt = blockIdx.y & 15;
  const int off0 = ctrl[16 + e], off1 = ctrl[16 + e + 1];
  const int row0 = off0 + mt * 128;
  if (row0 >= off1) return;
  const int n0 = blockIdx.x * 128;
  const int tid = threadIdx.x, lane = tid & 63, wv = tid >> 6;
  const int wr = wv >> 1, wc = wv & 1;
  const float* w1e = w1 + (size_t)e * Hh * Ff;
  const float* w3e = w3 + (size_t)e * Hh * Ff;
  f32x4 acc1[4][4] = {};
  f32x4 acc3[4][4] = {};
  const int sg = tid >> 6, snl = tid & 63;
  const int arow = wv * 16 + (lane >> 2), achk = lane & 3;

  for (int k0 = 0; k0 < Hh; k0 += 32) {
    __syncthreads();
    gload_lds16(Xg + (size_t)(row0 + arow) * Hh + k0 + achk * 8,
                (char*)sA + wv * 1024);
    gload_lds16(Xg + (size_t)(row0 + 64 + arow) * Hh + k0 + achk * 8,
                (char*)sA + 4096 + wv * 1024);
#pragma unroll
    for (int h = 0; h < 2; ++h) {
      int n = snl + 64 * h;
      const float* p1 = w1e + (size_t)(k0 + 8 * sg) * Ff + n0 + n;
      const float* p3 = w3e + (size_t)(k0 + 8 * sg) * Ff + n0 + n;
      unsigned int q1[4], q3[4];
#pragma unroll
      for (int j = 0; j < 4; ++j) {
        q1[j] = (unsigned)f2bf(p1[(size_t)(2 * j) * Ff]) |
                ((unsigned)f2bf(p1[(size_t)(2 * j + 1) * Ff]) << 16);
        q3[j] = (unsigned)f2bf(p3[(size_t)(2 * j) * Ff]) |
                ((unsigned)f2bf(p3[(size_t)(2 * j + 1) * Ff]) << 16);
      }
      *(uint4*)&sB1[n * 40 + 8 * sg] = make_uint4(q1[0], q1[1], q1[2], q1[3]);
      *(uint4*)&sB3[n * 40 + 8 * sg] = make_uint4(q3[0], q3[1], q3[2], q3[3]);
    }
    __syncthreads();
    bf16x8 af[4];
#pragma unroll
    for (int mi = 0; mi < 4; ++mi)
      af[mi] = *(const bf16x8*)&sA[(wr * 64 + mi * 16 + (lane & 15)) * 32 + 8 * (lane >> 4)];
#pragma unroll
    for (int ni = 0; ni < 4; ++ni) {
      bf16x8 b1 = *(const bf16x8*)&sB1[(wc * 64 + ni * 16 + (lane & 15)) * 40 + 8 * (lane >> 4)];
      bf16x8 b3 = *(const bf16x8*)&sB3[(wc * 64 + ni * 16 + (lane & 15)) * 40 + 8 * (lane >> 4)];
#pragma unroll
      for (int mi = 0; mi < 4; ++mi) {
        acc1[mi][ni] = __builtin_amdgcn_mfma_f32_16x16x32_bf16(af[mi], b1, acc1[mi][ni], 0, 0, 0);
        acc3[mi][ni] = __builtin_amdgcn_mfma_f32_16x16x32_bf16(af[mi], b3, acc3[mi][ni], 0, 0, 0);
      }
    }
  }
  const int rb = wr * 64 + 4 * (lane >> 4), cb = wc * 64 + (lane & 15);
#pragma unroll
  for (int mi = 0; mi < 4; ++mi)
#pragma unroll
    for (int ni = 0; ni < 4; ++ni)
#pragma unroll
      for (int r = 0; r < 4; ++r) {
        float h1 = acc1[mi][ni][r], h3 = acc3[mi][ni][r];
        float gv = h1 / (1.f + __expf(-h1)) * h3;
        G[(size_t)(row0 + rb + mi * 16 + r) * Ff + n0 + cb + ni * 16] = f2bf(gv);
      }
}

// ---------- stage B: out[t] += w * (G@w2), BM=64 BN=128 BK=32 ----------
__global__ __launch_bounds__(256, 2) void ffn2_kernel(
    const unsigned short* __restrict__ G, const float* __restrict__ w2,
    const int* __restrict__ ctrl, const int* __restrict__ rowmap,
    const float* __restrict__ roww, float* __restrict__ out) {
  __shared__ unsigned short sA[64 * 32];
  __shared__ unsigned short sB[128 * 40];
  const int e = blockIdx.y >> 5, mt = blockIdx.y & 31;
  const int off0 = ctrl[16 + e], off1 = ctrl[16 + e + 1];
  const int row0 = off0 + mt * 64;
  if (row0 >= off1) return;
  const int n0 = blockIdx.x * 128;
  const int tid = threadIdx.x, lane = tid & 63, wv = tid >> 6;
  const int wr = wv >> 1, wc = wv & 1;
  const float* w2e = w2 + (size_t)e * Ff * Hh;
  f32x4 acc[2][4] = {};
  const int sg = tid >> 6, snl = tid & 63;
  const int arow = wv * 16 + (lane >> 2), achk = lane & 3;

  for (int k0 = 0; k0 < Ff; k0 += 32) {
    __syncthreads();
    gload_lds16(G + (size_t)(row0 + arow) * Ff + k0 + achk * 8,
                (char*)sA + wv * 1024);
#pragma unroll
    for (int h = 0; h < 2; ++h) {
      int n = snl + 64 * h;
      const float* p2 = w2e + (size_t)(k0 + 8 * sg) * Hh + n0 + n;
      unsigned int q[4];
#pragma unroll
      for (int j = 0; j < 4; ++j)
        q[j] = (unsigned)f2bf(p2[(size_t)(2 * j) * Hh]) |
               ((unsigned)f2bf(p2[(size_t)(2 * j + 1) * Hh]) << 16);
      *(uint4*)&sB[n * 40 + 8 * sg] = make_uint4(q[0], q[1], q[2], q[3]);
    }
    __syncthreads();
    bf16x8 af[2];
#pragma unroll
    for (int mi = 0; mi < 2; ++mi)
      af[mi] = *(const bf16x8*)&sA[(wr * 32 + mi * 16 + (lane & 15)) * 32 + 8 * (lane >> 4)];
#pragma unroll
    for (int ni = 0; ni < 4; ++ni) {
      bf16x8 b = *(const bf16x8*)&sB[(wc * 64 + ni * 16 + (lane & 15)) * 40 + 8 * (lane >> 4)];
#pragma unroll
      for (int mi = 0; mi < 2; ++mi)
        acc[mi][ni] = __builtin_amdgcn_mfma_f32_16x16x32_bf16(af[mi], b, acc[mi][ni], 0, 0, 0);
    }
  }
  const int rb = wr * 32 + 4 * (lane >> 4), cb = wc * 64 + (lane & 15);
#pragma unroll
  for (int mi = 0; mi < 2; ++mi)
#pragma unroll
    for (int r = 0; r < 4; ++r) {
      int grow = row0 + rb + mi * 16 + r;
      int t = rowmap[grow];
      if (t < 0) continue;
      float wgt = roww[grow];
#pragma unroll
      for (int ni = 0; ni < 4; ++ni)
        atomicAdd(&out[(size_t)t * Hh + n0 + cb + ni * 16], wgt * acc[mi][ni][r]);
    }
}

extern "C" void kernel_launch(void* const* d_in, const int* in_sizes, int n_in,
                              void* d_out, int out_size, void* d_ws, size_t ws_size,
                              hipStream_t stream) {
  const float* x  = (const float*)d_in[0];
  const float* gw = (const float*)d_in[1];
  const float* w1 = (const float*)d_in[2];
  const float* w3 = (const float*)d_in[3];
  const float* w2 = (const float*)d_in[4];
  float* out = (float*)d_out;                      // [2048*1024]
  float* logits = out + (size_t)Tt * Hh;           // [2048*8]
  char* ws = (char*)d_ws;
  int* ctrl = (int*)(ws + OFF_CTRL);
  int* tok_e = (int*)(ws + OFF_TOKE);
  float* tok_w = (float*)(ws + OFF_TOKW);
  int* rowmap = (int*)(ws + OFF_ROWMAP);
  float* roww = (float*)(ws + OFF_ROWW);
  unsigned short* Xg = (unsigned short*)(ws + OFF_XG);
  unsigned short* G  = (unsigned short*)(ws + OFF_G);

  hipMemsetAsync(ctrl, 0, 256, stream);
  hipMemsetAsync(out, 0, (size_t)Tt * Hh * sizeof(float), stream);
  router_kernel<<<Tt / 4, 256, 0, stream>>>(x, gw, logits, tok_e, tok_w, ctrl);
  scan_assign_kernel<<<1, 256, 0, stream>>>(ctrl, tok_e, tok_w, rowmap, roww);
  gather_kernel<<<ROWS_CAP, 128, 0, stream>>>(x, ctrl, rowmap, Xg);
  ffn13_kernel<<<dim3(Ff / 128, Ee * 16), 256, 0, stream>>>(Xg, w1, w3, ctrl, G);
  ffn2_kernel<<<dim3(Hh / 128, Ee * 32), 256, 0, stream>>>(G, w2, ctrl, rowmap, roww, out);
}

// Round 2
// 425.623 us; speedup vs baseline: 1.2083x; 1.2083x over previous
//
#include <hip/hip_runtime.h>
#include <cstdint>
#include <cstddef>

#define Tt 2048
#define Hh 1024
#define Ff 3584
#define Ee 8
#define ROWS_CAP 5120

// ws layout (MiB offsets)
#define OFF_CTRL   0u
#define OFF_TOKE   256u
#define OFF_TOKW   (256u + 16384u)
#define OFF_ROWMAP (256u + 32768u)
#define OFF_ROWW   (256u + 32768u + 20480u)
#define OFF_XG     (1ull << 20)      // 10 MiB
#define OFF_G      (12ull << 20)     // 35 MiB
#define OFF_W1T    (48ull << 20)     // 56 MiB
#define OFF_W3T    (104ull << 20)    // 56 MiB
#define OFF_W2T    (160ull << 20)    // 56 MiB
#define WS_NEED    (216ull << 20)

typedef __attribute__((ext_vector_type(8))) short bf16x8;
typedef __attribute__((ext_vector_type(4))) float f32x4;

__device__ __forceinline__ unsigned short f2bf(float f) {
  unsigned int u = __float_as_uint(f);
  u += 0x7fffu + ((u >> 16) & 1u);
  return (unsigned short)(u >> 16);
}

__device__ __forceinline__ void gload_lds16(const void* g, void* l) {
  auto gp = (const __attribute__((address_space(1))) char*)(uintptr_t)g;
  auto lp = (__attribute__((address_space(3))) char*)(uintptr_t)l;
  __builtin_amdgcn_global_load_lds(gp, lp, 16, 0, 0);
}

// ---------------- router ----------------
__global__ __launch_bounds__(256) void router_kernel(
    const float* __restrict__ x, const float* __restrict__ gw,
    float* __restrict__ logits_out, int* __restrict__ tok_e,
    float* __restrict__ tok_w, int* __restrict__ ctrl) {
  const int lane = threadIdx.x & 63;
  const int t = blockIdx.x * 4 + (threadIdx.x >> 6);
  const float4* xp = (const float4*)(x + (size_t)t * Hh + lane * 16);
  float4 x0 = xp[0], x1 = xp[1], x2 = xp[2], x3 = xp[3];
  float lg[Ee];
#pragma unroll
  for (int e = 0; e < Ee; ++e) {
    const float4* gp = (const float4*)(gw + e * Hh + lane * 16);
    float4 g0 = gp[0], g1 = gp[1], g2 = gp[2], g3 = gp[3];
    float s = x0.x*g0.x + x0.y*g0.y + x0.z*g0.z + x0.w*g0.w
            + x1.x*g1.x + x1.y*g1.y + x1.z*g1.z + x1.w*g1.w
            + x2.x*g2.x + x2.y*g2.y + x2.z*g2.z + x2.w*g2.w
            + x3.x*g3.x + x3.y*g3.y + x3.z*g3.z + x3.w*g3.w;
#pragma unroll
    for (int o = 32; o; o >>= 1) s += __shfl_xor(s, o);
    lg[e] = s;
  }
  if (lane == 0) {
    float m = lg[0];
#pragma unroll
    for (int e = 1; e < Ee; ++e) m = fmaxf(m, lg[e]);
    float p[Ee];
#pragma unroll
    for (int e = 0; e < Ee; ++e) p[e] = expf(lg[e] - m);
    int a0 = 0;
#pragma unroll
    for (int e = 1; e < Ee; ++e) if (p[e] > p[a0]) a0 = e;
    int a1 = (a0 == 0) ? 1 : 0;
#pragma unroll
    for (int e = 0; e < Ee; ++e) if (e != a0 && p[e] > p[a1]) a1 = e;
    float rs = p[a0] + p[a1];
    float w0 = p[a0] / rs, w1 = p[a1] / rs;
#pragma unroll
    for (int e = 0; e < Ee; ++e) logits_out[(size_t)t * Ee + e] = lg[e];
    tok_e[t * 2] = a0; tok_e[t * 2 + 1] = a1;
    tok_w[t * 2] = w0; tok_w[t * 2 + 1] = w1;
    atomicAdd(&ctrl[a0], 1); atomicAdd(&ctrl[a1], 1);
  }
}

// ------------- scan + assign -------------
__global__ void scan_assign_kernel(int* ctrl, const int* __restrict__ tok_e,
                                   const float* __restrict__ tok_w,
                                   int* __restrict__ rowmap, float* __restrict__ roww) {
  if (threadIdx.x == 0) {
    int acc = 0;
    for (int e = 0; e < Ee; ++e) {
      ctrl[16 + e] = acc;
      acc += ((ctrl[e] + 127) >> 7) << 7;
    }
    ctrl[16 + Ee] = acc;
  }
  __syncthreads();
  for (int i = threadIdx.x; i < 2 * Tt; i += blockDim.x) {
    int e = tok_e[i];
    int pos = atomicAdd(&ctrl[8 + e], 1);
    int r = ctrl[16 + e] + pos;
    rowmap[r] = i >> 1;
    roww[r] = tok_w[i];
  }
  for (int i = threadIdx.x; i < Ee * 128; i += blockDim.x) {
    int e = i >> 7, pd = i & 127;
    int o = ctrl[16 + e], o1 = ctrl[16 + e + 1], c = ctrl[e];
    int r = o + c + pd;
    if (r < o1) { rowmap[r] = -1; roww[r] = 0.f; }
  }
}

// ---------------- gather x rows -> bf16 Xg ----------------
__global__ __launch_bounds__(128) void gather_kernel(
    const float* __restrict__ x, const int* __restrict__ ctrl,
    const int* __restrict__ rowmap, unsigned short* __restrict__ Xg) {
  int r = blockIdx.x;
  if (r >= ctrl[16 + Ee]) return;
  int t = rowmap[r];
  int j = threadIdx.x;
  uint4 v = make_uint4(0u, 0u, 0u, 0u);
  if (t >= 0) {
    const float4* xp = (const float4*)(x + (size_t)t * Hh + j * 8);
    float4 a = xp[0], b = xp[1];
    v.x = (unsigned)f2bf(a.x) | ((unsigned)f2bf(a.y) << 16);
    v.y = (unsigned)f2bf(a.z) | ((unsigned)f2bf(a.w) << 16);
    v.z = (unsigned)f2bf(b.x) | ((unsigned)f2bf(b.y) << 16);
    v.w = (unsigned)f2bf(b.z) | ((unsigned)f2bf(b.w) << 16);
  }
  *(uint4*)(Xg + (size_t)r * Hh + j * 8) = v;
}

// -------- transpose-convert: W fp32 [R][C] -> WT bf16 [C][R], per expert --------
__global__ __launch_bounds__(256) void tc_kernel(
    const float* __restrict__ in, unsigned short* __restrict__ out,
    int R, int C, int tiles_c) {
  __shared__ unsigned short sT[64 * 72];
  const int e = blockIdx.y;
  const int tr = blockIdx.x / tiles_c, tc = blockIdx.x % tiles_c;
  const int r0 = tr * 64, c0 = tc * 64;
  const float* src = in + (size_t)e * R * C;
  unsigned short* dst = out + (size_t)e * R * C;
  const int t = threadIdx.x;
#pragma unroll
  for (int p = 0; p < 4; ++p) {
    int row = p * 16 + (t >> 4);
    float4 v = *(const float4*)(src + (size_t)(r0 + row) * C + c0 + (t & 15) * 4);
    int cl = (t & 15) * 4;
    sT[(cl + 0) * 72 + row] = f2bf(v.x);
    sT[(cl + 1) * 72 + row] = f2bf(v.y);
    sT[(cl + 2) * 72 + row] = f2bf(v.z);
    sT[(cl + 3) * 72 + row] = f2bf(v.w);
  }
  __syncthreads();
  const int oc = t >> 2, half = t & 3;
  uint4 u0 = *(const uint4*)&sT[oc * 72 + half * 16];
  uint4 u1 = *(const uint4*)&sT[oc * 72 + half * 16 + 8];
  unsigned short* op = dst + (size_t)(c0 + oc) * R + r0 + half * 16;
  *(uint4*)op = u0;
  *(uint4*)(op + 8) = u1;
}

// -------- staging: 128x64 bf16 tile, chunk-XOR swizzled, via global_load_lds --------
// LDS holds: elem(row, k-chunk gc) at byte row*128 + (gc ^ (row&7))*16
__device__ __forceinline__ void stage_tile128(
    const unsigned short* __restrict__ src, size_t ld, int row0, int k0,
    char* lds, int wv, int l) {
#pragma unroll
  for (int p = 0; p < 4; ++p) {
    int rbase = wv * 32 + p * 8;
    int r = rbase + (l >> 3);
    int gc = (l & 7) ^ (l >> 3);
    gload_lds16(src + (size_t)(row0 + r) * ld + k0 + gc * 8, lds + rbase * 128);
  }
}

__device__ __forceinline__ bf16x8 frag(const unsigned short* s, int row, int gc) {
  return *(const bf16x8*)&s[row * 64 + ((gc ^ (row & 7)) * 8)];
}

// ---------- stage A GEMM: G = silu(Xg@w1T^T) * (Xg@w3T^T), BM=BN=128, BK=64 ----------
__global__ __launch_bounds__(256, 2) void ffn13_bf16(
    const unsigned short* __restrict__ Xg, const unsigned short* __restrict__ w1T,
    const unsigned short* __restrict__ w3T, const int* __restrict__ ctrl,
    unsigned short* __restrict__ G) {
  __shared__ unsigned short sA[128 * 64];
  __shared__ unsigned short sB1[128 * 64];
  __shared__ unsigned short sB3[128 * 64];
  const int e = blockIdx.y >> 4, mt = blockIdx.y & 15;
  const int off0 = ctrl[16 + e], off1 = ctrl[16 + e + 1];
  const int row0 = off0 + mt * 128;
  if (row0 >= off1) return;
  const int n0 = blockIdx.x * 128;
  const int tid = threadIdx.x, lane = tid & 63, wv = tid >> 6;
  const int wr = wv >> 1, wc = wv & 1;
  const unsigned short* w1e = w1T + (size_t)e * Ff * Hh;  // [F][H]
  const unsigned short* w3e = w3T + (size_t)e * Ff * Hh;
  f32x4 acc1[4][4] = {};
  f32x4 acc3[4][4] = {};

  for (int k0 = 0; k0 < Hh; k0 += 64) {
    __syncthreads();
    stage_tile128(Xg, Hh, row0, k0, (char*)sA, wv, lane);
    stage_tile128(w1e, Hh, n0, k0, (char*)sB1, wv, lane);
    stage_tile128(w3e, Hh, n0, k0, (char*)sB3, wv, lane);
    __syncthreads();
#pragma unroll
    for (int kk = 0; kk < 2; ++kk) {
      const int gc = kk * 4 + (lane >> 4);
      bf16x8 af[4];
#pragma unroll
      for (int mi = 0; mi < 4; ++mi)
        af[mi] = frag(sA, wr * 64 + mi * 16 + (lane & 15), gc);
#pragma unroll
      for (int ni = 0; ni < 4; ++ni) {
        bf16x8 b1 = frag(sB1, wc * 64 + ni * 16 + (lane & 15), gc);
        bf16x8 b3 = frag(sB3, wc * 64 + ni * 16 + (lane & 15), gc);
#pragma unroll
        for (int mi = 0; mi < 4; ++mi) {
          acc1[mi][ni] = __builtin_amdgcn_mfma_f32_16x16x32_bf16(af[mi], b1, acc1[mi][ni], 0, 0, 0);
          acc3[mi][ni] = __builtin_amdgcn_mfma_f32_16x16x32_bf16(af[mi], b3, acc3[mi][ni], 0, 0, 0);
        }
      }
    }
  }
  const int rb = wr * 64 + 4 * (lane >> 4), cb = wc * 64 + (lane & 15);
#pragma unroll
  for (int mi = 0; mi < 4; ++mi)
#pragma unroll
    for (int ni = 0; ni < 4; ++ni)
#pragma unroll
      for (int r = 0; r < 4; ++r) {
        float h1 = acc1[mi][ni][r], h3 = acc3[mi][ni][r];
        float gv = h1 / (1.f + __expf(-h1)) * h3;
        G[(size_t)(row0 + rb + mi * 16 + r) * Ff + n0 + cb + ni * 16] = f2bf(gv);
      }
}

// ---------- stage B GEMM: out[t] += w * (G@w2T^T), BM=BN=128, BK=64 ----------
__global__ __launch_bounds__(256, 2) void ffn2_bf16(
    const unsigned short* __restrict__ G, const unsigned short* __restrict__ w2T,
    const int* __restrict__ ctrl, const int* __restrict__ rowmap,
    const float* __restrict__ roww, float* __restrict__ out) {
  __shared__ unsigned short sA[128 * 64];
  __shared__ unsigned short sB[128 * 64];
  const int e = blockIdx.y >> 4, mt = blockIdx.y & 15;
  const int off0 = ctrl[16 + e], off1 = ctrl[16 + e + 1];
  const int row0 = off0 + mt * 128;
  if (row0 >= off1) return;
  const int n0 = blockIdx.x * 128;
  const int tid = threadIdx.x, lane = tid & 63, wv = tid >> 6;
  const int wr = wv >> 1, wc = wv & 1;
  const unsigned short* w2e = w2T + (size_t)e * Ff * Hh;  // [H][F]
  f32x4 acc[4][4] = {};

  for (int k0 = 0; k0 < Ff; k0 += 64) {
    __syncthreads();
    stage_tile128(G, Ff, row0, k0, (char*)sA, wv, lane);
    stage_tile128(w2e, Ff, n0, k0, (char*)sB, wv, lane);
    __syncthreads();
#pragma unroll
    for (int kk = 0; kk < 2; ++kk) {
      const int gc = kk * 4 + (lane >> 4);
      bf16x8 af[4];
#pragma unroll
      for (int mi = 0; mi < 4; ++mi)
        af[mi] = frag(sA, wr * 64 + mi * 16 + (lane & 15), gc);
#pragma unroll
      for (int ni = 0; ni < 4; ++ni) {
        bf16x8 b = frag(sB, wc * 64 + ni * 16 + (lane & 15), gc);
#pragma unroll
        for (int mi = 0; mi < 4; ++mi)
          acc[mi][ni] = __builtin_amdgcn_mfma_f32_16x16x32_bf16(af[mi], b, acc[mi][ni], 0, 0, 0);
      }
    }
  }
  const int rb = wr * 64 + 4 * (lane >> 4), cb = wc * 64 + (lane & 15);
#pragma unroll
  for (int mi = 0; mi < 4; ++mi)
#pragma unroll
    for (int r = 0; r < 4; ++r) {
      int grow = row0 + rb + mi * 16 + r;
      int t = rowmap[grow];
      if (t < 0) continue;
      float wgt = roww[grow];
#pragma unroll
      for (int ni = 0; ni < 4; ++ni)
        atomicAdd(&out[(size_t)t * Hh + n0 + cb + ni * 16], wgt * acc[mi][ni][r]);
    }
}

// ================= fallback (round-1) kernels, used if ws too small =================
__global__ __launch_bounds__(256, 2) void ffn13_fb(
    const unsigned short* __restrict__ Xg, const float* __restrict__ w1,
    const float* __restrict__ w3, const int* __restrict__ ctrl,
    unsigned short* __restrict__ G) {
  __shared__ unsigned short sA[128 * 32];
  __shared__ unsigned short sB1[128 * 40];
  __shared__ unsigned short sB3[128 * 40];
  const int e = blockIdx.y >> 4, mt = blockIdx.y & 15;
  const int off0 = ctrl[16 + e], off1 = ctrl[16 + e + 1];
  const int row0 = off0 + mt * 128;
  if (row0 >= off1) return;
  const int n0 = blockIdx.x * 128;
  const int tid = threadIdx.x, lane = tid & 63, wv = tid >> 6;
  const int wr = wv >> 1, wc = wv & 1;
  const float* w1e = w1 + (size_t)e * Hh * Ff;
  const float* w3e = w3 + (size_t)e * Hh * Ff;
  f32x4 acc1[4][4] = {};
  f32x4 acc3[4][4] = {};
  const int sg = tid >> 6, snl = tid & 63;
  const int arow = wv * 16 + (lane >> 2), achk = lane & 3;
  for (int k0 = 0; k0 < Hh; k0 += 32) {
    __syncthreads();
    gload_lds16(Xg + (size_t)(row0 + arow) * Hh + k0 + achk * 8, (char*)sA + wv * 1024);
    gload_lds16(Xg + (size_t)(row0 + 64 + arow) * Hh + k0 + achk * 8, (char*)sA + 4096 + wv * 1024);
#pragma unroll
    for (int h = 0; h < 2; ++h) {
      int n = snl + 64 * h;
      const float* p1 = w1e + (size_t)(k0 + 8 * sg) * Ff + n0 + n;
      const float* p3 = w3e + (size_t)(k0 + 8 * sg) * Ff + n0 + n;
      unsigned int q1[4], q3[4];
#pragma unroll
      for (int j = 0; j < 4; ++j) {
        q1[j] = (unsigned)f2bf(p1[(size_t)(2 * j) * Ff]) | ((unsigned)f2bf(p1[(size_t)(2 * j + 1) * Ff]) << 16);
        q3[j] = (unsigned)f2bf(p3[(size_t)(2 * j) * Ff]) | ((unsigned)f2bf(p3[(size_t)(2 * j + 1) * Ff]) << 16);
      }
      *(uint4*)&sB1[n * 40 + 8 * sg] = make_uint4(q1[0], q1[1], q1[2], q1[3]);
      *(uint4*)&sB3[n * 40 + 8 * sg] = make_uint4(q3[0], q3[1], q3[2], q3[3]);
    }
    __syncthreads();
    bf16x8 af[4];
#pragma unroll
    for (int mi = 0; mi < 4; ++mi)
      af[mi] = *(const bf16x8*)&sA[(wr * 64 + mi * 16 + (lane & 15)) * 32 + 8 * (lane >> 4)];
#pragma unroll
    for (int ni = 0; ni < 4; ++ni) {
      bf16x8 b1 = *(const bf16x8*)&sB1[(wc * 64 + ni * 16 + (lane & 15)) * 40 + 8 * (lane >> 4)];
      bf16x8 b3 = *(const bf16x8*)&sB3[(wc * 64 + ni * 16 + (lane & 15)) * 40 + 8 * (lane >> 4)];
#pragma unroll
      for (int mi = 0; mi < 4; ++mi) {
        acc1[mi][ni] = __builtin_amdgcn_mfma_f32_16x16x32_bf16(af[mi], b1, acc1[mi][ni], 0, 0, 0);
        acc3[mi][ni] = __builtin_amdgcn_mfma_f32_16x16x32_bf16(af[mi], b3, acc3[mi][ni], 0, 0, 0);
      }
    }
  }
  const int rb = wr * 64 + 4 * (lane >> 4), cb = wc * 64 + (lane & 15);
#pragma unroll
  for (int mi = 0; mi < 4; ++mi)
#pragma unroll
    for (int ni = 0; ni < 4; ++ni)
#pragma unroll
      for (int r = 0; r < 4; ++r) {
        float h1 = acc1[mi][ni][r], h3 = acc3[mi][ni][r];
        float gv = h1 / (1.f + __expf(-h1)) * h3;
        G[(size_t)(row0 + rb + mi * 16 + r) * Ff + n0 + cb + ni * 16] = f2bf(gv);
      }
}

__global__ __launch_bounds__(256, 2) void ffn2_fb(
    const unsigned short* __restrict__ G, const float* __restrict__ w2,
    const int* __restrict__ ctrl, const int* __restrict__ rowmap,
    const float* __restrict__ roww, float* __restrict__ out) {
  __shared__ unsigned short sA[64 * 32];
  __shared__ unsigned short sB[128 * 40];
  const int e = blockIdx.y >> 5, mt = blockIdx.y & 31;
  const int off0 = ctrl[16 + e], off1 = ctrl[16 + e + 1];
  const int row0 = off0 + mt * 64;
  if (row0 >= off1) return;
  const int n0 = blockIdx.x * 128;
  const int tid = threadIdx.x, lane = tid & 63, wv = tid >> 6;
  const int wr = wv >> 1, wc = wv & 1;
  const float* w2e = w2 + (size_t)e * Ff * Hh;
  f32x4 acc[2][4] = {};
  const int sg = tid >> 6, snl = tid & 63;
  const int arow = wv * 16 + (lane >> 2), achk = lane & 3;
  for (int k0 = 0; k0 < Ff; k0 += 32) {
    __syncthreads();
    gload_lds16(G + (size_t)(row0 + arow) * Ff + k0 + achk * 8, (char*)sA + wv * 1024);
#pragma unroll
    for (int h = 0; h < 2; ++h) {
      int n = snl + 64 * h;
      const float* p2 = w2e + (size_t)(k0 + 8 * sg) * Hh + n0 + n;
      unsigned int q[4];
#pragma unroll
      for (int j = 0; j < 4; ++j)
        q[j] = (unsigned)f2bf(p2[(size_t)(2 * j) * Hh]) | ((unsigned)f2bf(p2[(size_t)(2 * j + 1) * Hh]) << 16);
      *(uint4*)&sB[n * 40 + 8 * sg] = make_uint4(q[0], q[1], q[2], q[3]);
    }
    __syncthreads();
    bf16x8 af[2];
#pragma unroll
    for (int mi = 0; mi < 2; ++mi)
      af[mi] = *(const bf16x8*)&sA[(wr * 32 + mi * 16 + (lane & 15)) * 32 + 8 * (lane >> 4)];
#pragma unroll
    for (int ni = 0; ni < 4; ++ni) {
      bf16x8 b = *(const bf16x8*)&sB[(wc * 64 + ni * 16 + (lane & 15)) * 40 + 8 * (lane >> 4)];
#pragma unroll
      for (int mi = 0; mi < 2; ++mi)
        acc[mi][ni] = __builtin_amdgcn_mfma_f32_16x16x32_bf16(af[mi], b, acc[mi][ni], 0, 0, 0);
    }
  }
  const int rb = wr * 32 + 4 * (lane >> 4), cb = wc * 64 + (lane & 15);
#pragma unroll
  for (int mi = 0; mi < 2; ++mi)
#pragma unroll
    for (int r = 0; r < 4; ++r) {
      int grow = row0 + rb + mi * 16 + r;
      int t = rowmap[grow];
      if (t < 0) continue;
      float wgt = roww[grow];
#pragma unroll
      for (int ni = 0; ni < 4; ++ni)
        atomicAdd(&out[(size_t)t * Hh + n0 + cb + ni * 16], wgt * acc[mi][ni][r]);
    }
}

extern "C" void kernel_launch(void* const* d_in, const int* in_sizes, int n_in,
                              void* d_out, int out_size, void* d_ws, size_t ws_size,
                              hipStream_t stream) {
  const float* x  = (const float*)d_in[0];
  const float* gw = (const float*)d_in[1];
  const float* w1 = (const float*)d_in[2];
  const float* w3 = (const float*)d_in[3];
  const float* w2 = (const float*)d_in[4];
  float* out = (float*)d_out;
  float* logits = out + (size_t)Tt * Hh;
  char* ws = (char*)d_ws;
  int* ctrl = (int*)(ws + OFF_CTRL);
  int* tok_e = (int*)(ws + OFF_TOKE);
  float* tok_w = (float*)(ws + OFF_TOKW);
  int* rowmap = (int*)(ws + OFF_ROWMAP);
  float* roww = (float*)(ws + OFF_ROWW);
  unsigned short* Xg = (unsigned short*)(ws + OFF_XG);
  unsigned short* G  = (unsigned short*)(ws + OFF_G);
  unsigned short* w1T = (unsigned short*)(ws + OFF_W1T);
  unsigned short* w3T = (unsigned short*)(ws + OFF_W3T);
  unsigned short* w2T = (unsigned short*)(ws + OFF_W2T);

  hipMemsetAsync(ctrl, 0, 256, stream);
  hipMemsetAsync(out, 0, (size_t)Tt * Hh * sizeof(float), stream);
  router_kernel<<<Tt / 4, 256, 0, stream>>>(x, gw, logits, tok_e, tok_w, ctrl);
  scan_assign_kernel<<<1, 256, 0, stream>>>(ctrl, tok_e, tok_w, rowmap, roww);
  gather_kernel<<<ROWS_CAP, 128, 0, stream>>>(x, ctrl, rowmap, Xg);

  if (ws_size >= WS_NEED) {
    tc_kernel<<<dim3(16 * 56, Ee), 256, 0, stream>>>(w1, w1T, Hh, Ff, 56);
    tc_kernel<<<dim3(16 * 56, Ee), 256, 0, stream>>>(w3, w3T, Hh, Ff, 56);
    tc_kernel<<<dim3(56 * 16, Ee), 256, 0, stream>>>(w2, w2T, Ff, Hh, 16);
    ffn13_bf16<<<dim3(Ff / 128, Ee * 16), 256, 0, stream>>>(Xg, w1T, w3T, ctrl, G);
    ffn2_bf16<<<dim3(Hh / 128, Ee * 16), 256, 0, stream>>>(G, w2T, ctrl, rowmap, roww, out);
  } else {
    ffn13_fb<<<dim3(Ff / 128, Ee * 16), 256, 0, stream>>>(Xg, w1, w3, ctrl, G);
    ffn2_fb<<<dim3(Hh / 128, Ee * 32), 256, 0, stream>>>(G, w2, ctrl, rowmap, roww, out);
  }
}

// Round 3
// 372.787 us; speedup vs baseline: 1.3796x; 1.1417x over previous
//
#include <hip/hip_runtime.h>
#include <cstdint>
#include <cstddef>

#define Tt 2048
#define Hh 1024
#define Ff 3584
#define Ee 8
#define ROWS_CAP 5120

#define OFF_CTRL   0u
#define OFF_TOKE   256u
#define OFF_TOKW   (256u + 16384u)
#define OFF_ROWMAP (256u + 32768u)
#define OFF_ROWW   (256u + 32768u + 20480u)
#define OFF_XG     (1ull << 20)
#define OFF_G      (12ull << 20)
#define OFF_W1T    (48ull << 20)
#define OFF_W3T    (104ull << 20)
#define OFF_W2T    (160ull << 20)

typedef __attribute__((ext_vector_type(8))) short bf16x8;
typedef __attribute__((ext_vector_type(4))) float f32x4;

__device__ __forceinline__ unsigned short f2bf(float f) {
  unsigned int u = __float_as_uint(f);
  u += 0x7fffu + ((u >> 16) & 1u);
  return (unsigned short)(u >> 16);
}

__device__ __forceinline__ void gload_lds16(const void* g, void* l) {
  auto gp = (const __attribute__((address_space(1))) char*)(uintptr_t)g;
  auto lp = (__attribute__((address_space(3))) char*)(uintptr_t)l;
  __builtin_amdgcn_global_load_lds(gp, lp, 16, 0, 0);
}

// LDS tile: 128 rows x 32 k bf16 (64 B/row). pos = gc ^ ((row>>1)&3):
// 16 consecutive rows hit all 8 bank-groups -> 2-way only (free).
__device__ __forceinline__ bf16x8 frg(const char* lds, int row, int gc) {
  return *(const bf16x8*)(lds + row * 64 + ((gc ^ ((row >> 1) & 3)) * 16));
}

// ---------------- router ----------------
__global__ __launch_bounds__(256) void router_kernel(
    const float* __restrict__ x, const float* __restrict__ gw,
    float* __restrict__ logits_out, int* __restrict__ tok_e,
    float* __restrict__ tok_w, int* __restrict__ ctrl) {
  const int lane = threadIdx.x & 63;
  const int t = blockIdx.x * 4 + (threadIdx.x >> 6);
  const float4* xp = (const float4*)(x + (size_t)t * Hh + lane * 16);
  float4 x0 = xp[0], x1 = xp[1], x2 = xp[2], x3 = xp[3];
  float lg[Ee];
#pragma unroll
  for (int e = 0; e < Ee; ++e) {
    const float4* gp = (const float4*)(gw + e * Hh + lane * 16);
    float4 g0 = gp[0], g1 = gp[1], g2 = gp[2], g3 = gp[3];
    float s = x0.x*g0.x + x0.y*g0.y + x0.z*g0.z + x0.w*g0.w
            + x1.x*g1.x + x1.y*g1.y + x1.z*g1.z + x1.w*g1.w
            + x2.x*g2.x + x2.y*g2.y + x2.z*g2.z + x2.w*g2.w
            + x3.x*g3.x + x3.y*g3.y + x3.z*g3.z + x3.w*g3.w;
#pragma unroll
    for (int o = 32; o; o >>= 1) s += __shfl_xor(s, o);
    lg[e] = s;
  }
  if (lane == 0) {
    float m = lg[0];
#pragma unroll
    for (int e = 1; e < Ee; ++e) m = fmaxf(m, lg[e]);
    float p[Ee];
#pragma unroll
    for (int e = 0; e < Ee; ++e) p[e] = expf(lg[e] - m);
    int a0 = 0;
#pragma unroll
    for (int e = 1; e < Ee; ++e) if (p[e] > p[a0]) a0 = e;
    int a1 = (a0 == 0) ? 1 : 0;
#pragma unroll
    for (int e = 0; e < Ee; ++e) if (e != a0 && p[e] > p[a1]) a1 = e;
    float rs = p[a0] + p[a1];
    float w0 = p[a0] / rs, w1 = p[a1] / rs;
#pragma unroll
    for (int e = 0; e < Ee; ++e) logits_out[(size_t)t * Ee + e] = lg[e];
    tok_e[t * 2] = a0; tok_e[t * 2 + 1] = a1;
    tok_w[t * 2] = w0; tok_w[t * 2 + 1] = w1;
    atomicAdd(&ctrl[a0], 1); atomicAdd(&ctrl[a1], 1);
  }
}

__global__ void offsets_kernel(int* ctrl) {
  if (threadIdx.x == 0) {
    int acc = 0;
    for (int e = 0; e < Ee; ++e) {
      ctrl[16 + e] = acc;
      acc += ((ctrl[e] + 127) >> 7) << 7;
    }
    ctrl[16 + Ee] = acc;
  }
}

__global__ __launch_bounds__(512) void assign_kernel(
    int* ctrl, const int* __restrict__ tok_e, const float* __restrict__ tok_w,
    int* __restrict__ rowmap, float* __restrict__ roww) {
  int i = blockIdx.x * 512 + threadIdx.x;
  if (i < 2 * Tt) {
    int e = tok_e[i];
    int pos = atomicAdd(&ctrl[8 + e], 1);
    int r = ctrl[16 + e] + pos;
    rowmap[r] = i >> 1;
    roww[r] = tok_w[i];
  }
  if (i < Ee * 128) {
    int e = i >> 7, pd = i & 127;
    int o = ctrl[16 + e], o1 = ctrl[16 + e + 1], c = ctrl[e];
    int r = o + c + pd;
    if (r < o1) { rowmap[r] = -1; roww[r] = 0.f; }
  }
}

// ---------------- gather x rows -> bf16 Xg ----------------
__global__ __launch_bounds__(128) void gather_kernel(
    const float* __restrict__ x, const int* __restrict__ ctrl,
    const int* __restrict__ rowmap, unsigned short* __restrict__ Xg) {
  int r = blockIdx.x;
  if (r >= ctrl[16 + Ee]) return;
  int t = rowmap[r];
  int j = threadIdx.x;
  uint4 v = make_uint4(0u, 0u, 0u, 0u);
  if (t >= 0) {
    const float4* xp = (const float4*)(x + (size_t)t * Hh + j * 8);
    float4 a = xp[0], b = xp[1];
    v.x = (unsigned)f2bf(a.x) | ((unsigned)f2bf(a.y) << 16);
    v.y = (unsigned)f2bf(a.z) | ((unsigned)f2bf(a.w) << 16);
    v.z = (unsigned)f2bf(b.x) | ((unsigned)f2bf(b.y) << 16);
    v.w = (unsigned)f2bf(b.z) | ((unsigned)f2bf(b.w) << 16);
  }
  *(uint4*)(Xg + (size_t)r * Hh + j * 8) = v;
}

// -------- transpose-convert all three weights in one launch --------
__global__ __launch_bounds__(256) void tc_all(
    const float* __restrict__ w1, const float* __restrict__ w3,
    const float* __restrict__ w2, unsigned short* __restrict__ w1T,
    unsigned short* __restrict__ w3T, unsigned short* __restrict__ w2T) {
  __shared__ unsigned short sT[64 * 72];
  const int z = blockIdx.z;
  const float* in = (z == 0) ? w1 : (z == 1) ? w3 : w2;
  unsigned short* out = (z == 0) ? w1T : (z == 1) ? w3T : w2T;
  const int C = (z == 2) ? Hh : Ff;
  const int tiles_c = (z == 2) ? 16 : 56;
  const int R = (z == 2) ? Ff : Hh;
  const int e = blockIdx.y;
  const int tr = blockIdx.x / tiles_c, tc = blockIdx.x % tiles_c;
  const int r0 = tr * 64, c0 = tc * 64;
  const float* src = in + (size_t)e * R * C;
  unsigned short* dst = out + (size_t)e * R * C;
  const int t = threadIdx.x;
#pragma unroll
  for (int p = 0; p < 4; ++p) {
    int row = p * 16 + (t >> 4);
    float4 v = *(const float4*)(src + (size_t)(r0 + row) * C + c0 + (t & 15) * 4);
    int cl = (t & 15) * 4;
    sT[(cl + 0) * 72 + row] = f2bf(v.x);
    sT[(cl + 1) * 72 + row] = f2bf(v.y);
    sT[(cl + 2) * 72 + row] = f2bf(v.z);
    sT[(cl + 3) * 72 + row] = f2bf(v.w);
  }
  __syncthreads();
  const int oc = t >> 2, half = t & 3;
  uint4 u0 = *(const uint4*)&sT[oc * 72 + half * 16];
  uint4 u1 = *(const uint4*)&sT[oc * 72 + half * 16 + 8];
  unsigned short* op = dst + (size_t)(c0 + oc) * R + r0 + half * 16;
  *(uint4*)op = u0;
  *(uint4*)(op + 8) = u1;
}

// ---------- stage A GEMM: 512 thr, BM=BN=128, BK=32, dbuf 2-phase ----------
__global__ __launch_bounds__(512, 4) void ffn13_bf16(
    const unsigned short* __restrict__ Xg, const unsigned short* __restrict__ w1T,
    const unsigned short* __restrict__ w3T, const int* __restrict__ ctrl,
    unsigned short* __restrict__ G) {
  __shared__ alignas(16) char sA[2][8192], sB1[2][8192], sB3[2][8192];
  int lin = blockIdx.y * 28 + blockIdx.x;          // 3584 blocks, %8==0
  int wg = (lin & 7) * 448 + (lin >> 3);           // bijective XCD swizzle
  int bx = wg % 28, by = wg / 28;
  const int e = by >> 4, mt = by & 15;
  const int off0 = ctrl[16 + e], off1 = ctrl[16 + e + 1];
  const int row0 = off0 + mt * 128;
  if (row0 >= off1) return;
  const int n0 = bx * 128;
  const int tid = threadIdx.x, lane = tid & 63, wv = tid >> 6;
  const int wr = wv >> 2, wc = wv & 3;             // 2x4 wave grid, tile 64x32
  const unsigned short* w1e = w1T + (size_t)e * Ff * Hh;
  const unsigned short* w3e = w3T + (size_t)e * Ff * Hh;
  f32x4 acc1[4][2] = {};
  f32x4 acc3[4][2] = {};
  const int srow = wv * 16 + (lane >> 2);
  const int sgc = (lane & 3) ^ ((lane >> 3) & 3);
  const int swb = wv * 16;

  // prologue
  {
    size_t so = (size_t)sgc * 8;
    gload_lds16(Xg + (size_t)(row0 + srow) * Hh + so, sA[0] + swb * 64);
    gload_lds16(w1e + (size_t)(n0 + srow) * Hh + so, sB1[0] + swb * 64);
    gload_lds16(w3e + (size_t)(n0 + srow) * Hh + so, sB3[0] + swb * 64);
  }
  __syncthreads();
  for (int it = 0; it < 32; ++it) {
    int cur = it & 1;
    if (it < 31) {
      size_t so = (size_t)(it + 1) * 32 + sgc * 8;
      gload_lds16(Xg + (size_t)(row0 + srow) * Hh + so, sA[cur ^ 1] + swb * 64);
      gload_lds16(w1e + (size_t)(n0 + srow) * Hh + so, sB1[cur ^ 1] + swb * 64);
      gload_lds16(w3e + (size_t)(n0 + srow) * Hh + so, sB3[cur ^ 1] + swb * 64);
    }
    const int gc = lane >> 4;
    bf16x8 af[4];
#pragma unroll
    for (int mi = 0; mi < 4; ++mi)
      af[mi] = frg(sA[cur], wr * 64 + mi * 16 + (lane & 15), gc);
    __builtin_amdgcn_s_setprio(1);
#pragma unroll
    for (int ni = 0; ni < 2; ++ni) {
      bf16x8 b1 = frg(sB1[cur], wc * 32 + ni * 16 + (lane & 15), gc);
      bf16x8 b3 = frg(sB3[cur], wc * 32 + ni * 16 + (lane & 15), gc);
#pragma unroll
      for (int mi = 0; mi < 4; ++mi) {
        acc1[mi][ni] = __builtin_amdgcn_mfma_f32_16x16x32_bf16(af[mi], b1, acc1[mi][ni], 0, 0, 0);
        acc3[mi][ni] = __builtin_amdgcn_mfma_f32_16x16x32_bf16(af[mi], b3, acc3[mi][ni], 0, 0, 0);
      }
    }
    __builtin_amdgcn_s_setprio(0);
    __syncthreads();
  }
  const int rb = wr * 64 + 4 * (lane >> 4), cb = wc * 32 + (lane & 15);
#pragma unroll
  for (int mi = 0; mi < 4; ++mi)
#pragma unroll
    for (int ni = 0; ni < 2; ++ni)
#pragma unroll
      for (int r = 0; r < 4; ++r) {
        float h1 = acc1[mi][ni][r], h3 = acc3[mi][ni][r];
        float gv = h1 / (1.f + __expf(-h1)) * h3;
        G[(size_t)(row0 + rb + mi * 16 + r) * Ff + n0 + cb + ni * 16] = f2bf(gv);
      }
}

// ---------- stage B GEMM: 256 thr, BM=BN=128, BK=32, K-split x4, dbuf ----------
__global__ __launch_bounds__(256, 4) void ffn2_bf16(
    const unsigned short* __restrict__ G, const unsigned short* __restrict__ w2T,
    const int* __restrict__ ctrl, const int* __restrict__ rowmap,
    const float* __restrict__ roww, float* __restrict__ out) {
  __shared__ alignas(16) char sA[2][8192], sB[2][8192];
  int lin = blockIdx.y * 8 + blockIdx.x;           // 1024 per z-slice
  int wg = (lin & 7) * 128 + (lin >> 3);
  int bx = wg % 8, by = wg / 8;
  const int e = by >> 4, mt = by & 15;
  const int off0 = ctrl[16 + e], off1 = ctrl[16 + e + 1];
  const int row0 = off0 + mt * 128;
  if (row0 >= off1) return;
  const int n0 = bx * 128;
  const int kb = blockIdx.z * (Ff / 4);
  const int tid = threadIdx.x, lane = tid & 63, wv = tid >> 6;
  const int wr = wv >> 1, wc = wv & 1;             // 2x2 wave grid, tile 64x64
  const unsigned short* w2e = w2T + (size_t)e * Ff * Hh;
  f32x4 acc[4][4] = {};
  const int sl = lane >> 2;
  const int sgc = (lane & 3) ^ ((lane >> 3) & 3);

  // prologue
#pragma unroll
  for (int half = 0; half < 2; ++half) {
    int wb = wv * 16 + half * 64;
    size_t so = (size_t)kb + sgc * 8;
    gload_lds16(G + (size_t)(row0 + wb + sl) * Ff + so, sA[0] + wb * 64);
    gload_lds16(w2e + (size_t)(n0 + wb + sl) * Ff + so, sB[0] + wb * 64);
  }
  __syncthreads();
  for (int it = 0; it < 28; ++it) {
    int cur = it & 1;
    if (it < 27) {
#pragma unroll
      for (int half = 0; half < 2; ++half) {
        int wb = wv * 16 + half * 64;
        size_t so = (size_t)kb + (it + 1) * 32 + sgc * 8;
        gload_lds16(G + (size_t)(row0 + wb + sl) * Ff + so, sA[cur ^ 1] + wb * 64);
        gload_lds16(w2e + (size_t)(n0 + wb + sl) * Ff + so, sB[cur ^ 1] + wb * 64);
      }
    }
    const int gc = lane >> 4;
    bf16x8 af[4];
#pragma unroll
    for (int mi = 0; mi < 4; ++mi)
      af[mi] = frg(sA[cur], wr * 64 + mi * 16 + (lane & 15), gc);
    __builtin_amdgcn_s_setprio(1);
#pragma unroll
    for (int ni = 0; ni < 4; ++ni) {
      bf16x8 b = frg(sB[cur], wc * 64 + ni * 16 + (lane & 15), gc);
#pragma unroll
      for (int mi = 0; mi < 4; ++mi)
        acc[mi][ni] = __builtin_amdgcn_mfma_f32_16x16x32_bf16(af[mi], b, acc[mi][ni], 0, 0, 0);
    }
    __builtin_amdgcn_s_setprio(0);
    __syncthreads();
  }
  const int rb = wr * 64 + 4 * (lane >> 4), cb = wc * 64 + (lane & 15);
#pragma unroll
  for (int mi = 0; mi < 4; ++mi)
#pragma unroll
    for (int r = 0; r < 4; ++r) {
      int grow = row0 + rb + mi * 16 + r;
      int t = rowmap[grow];
      if (t < 0) continue;
      float wgt = roww[grow];
#pragma unroll
      for (int ni = 0; ni < 4; ++ni)
        atomicAdd(&out[(size_t)t * Hh + n0 + cb + ni * 16], wgt * acc[mi][ni][r]);
    }
}

extern "C" void kernel_launch(void* const* d_in, const int* in_sizes, int n_in,
                              void* d_out, int out_size, void* d_ws, size_t ws_size,
                              hipStream_t stream) {
  const float* x  = (const float*)d_in[0];
  const float* gw = (const float*)d_in[1];
  const float* w1 = (const float*)d_in[2];
  const float* w3 = (const float*)d_in[3];
  const float* w2 = (const float*)d_in[4];
  float* out = (float*)d_out;
  float* logits = out + (size_t)Tt * Hh;
  char* ws = (char*)d_ws;
  int* ctrl = (int*)(ws + OFF_CTRL);
  int* tok_e = (int*)(ws + OFF_TOKE);
  float* tok_w = (float*)(ws + OFF_TOKW);
  int* rowmap = (int*)(ws + OFF_ROWMAP);
  float* roww = (float*)(ws + OFF_ROWW);
  unsigned short* Xg = (unsigned short*)(ws + OFF_XG);
  unsigned short* G  = (unsigned short*)(ws + OFF_G);
  unsigned short* w1T = (unsigned short*)(ws + OFF_W1T);
  unsigned short* w3T = (unsigned short*)(ws + OFF_W3T);
  unsigned short* w2T = (unsigned short*)(ws + OFF_W2T);

  hipMemsetAsync(ctrl, 0, 256, stream);
  hipMemsetAsync(out, 0, (size_t)Tt * Hh * sizeof(float), stream);
  router_kernel<<<Tt / 4, 256, 0, stream>>>(x, gw, logits, tok_e, tok_w, ctrl);
  offsets_kernel<<<1, 64, 0, stream>>>(ctrl);
  assign_kernel<<<8, 512, 0, stream>>>(ctrl, tok_e, tok_w, rowmap, roww);
  gather_kernel<<<ROWS_CAP, 128, 0, stream>>>(x, ctrl, rowmap, Xg);
  tc_all<<<dim3(896, Ee, 3), 256, 0, stream>>>(w1, w3, w2, w1T, w3T, w2T);
  ffn13_bf16<<<dim3(28, Ee * 16), 512, 0, stream>>>(Xg, w1T, w3T, ctrl, G);
  ffn2_bf16<<<dim3(8, Ee * 16, 4), 256, 0, stream>>>(G, w2T, ctrl, rowmap, roww, out);
}

// Round 4
// 367.137 us; speedup vs baseline: 1.4008x; 1.0154x over previous
//
#include <hip/hip_runtime.h>
#include <cstdint>
#include <cstddef>

#define Tt 2048
#define Hh 1024
#define Ff 3584
#define Ee 8
#define ROWS_CAP 5120

#define OFF_CTRL   0u
#define OFF_TOKE   256u
#define OFF_TOKW   (256u + 16384u)
#define OFF_ROWMAP (256u + 32768u)
#define OFF_ROWW   (256u + 32768u + 20480u)
#define OFF_XG     (1ull << 20)
#define OFF_G      (12ull << 20)
#define OFF_W1T    (48ull << 20)
#define OFF_W3T    (104ull << 20)
#define OFF_W2T    (160ull << 20)

typedef __attribute__((ext_vector_type(8))) short bf16x8;
typedef __attribute__((ext_vector_type(4))) float f32x4;

__device__ __forceinline__ unsigned short f2bf(float f) {
  unsigned int u = __float_as_uint(f);
  u += 0x7fffu + ((u >> 16) & 1u);
  return (unsigned short)(u >> 16);
}

__device__ __forceinline__ void gload_lds16(const void* g, void* l) {
  auto gp = (const __attribute__((address_space(1))) char*)(uintptr_t)g;
  auto lp = (__attribute__((address_space(3))) char*)(uintptr_t)l;
  __builtin_amdgcn_global_load_lds(gp, lp, 16, 0, 0);
}

// GEMM LDS tile: 128 rows x 32 k bf16 (64 B/row). pos = gc ^ ((row>>1)&3).
__device__ __forceinline__ bf16x8 frg(const char* lds, int row, int gc) {
  return *(const bf16x8*)(lds + row * 64 + ((gc ^ ((row >> 1) & 3)) * 16));
}

// ---------------- router ----------------
__global__ __launch_bounds__(256) void router_kernel(
    const float* __restrict__ x, const float* __restrict__ gw,
    float* __restrict__ logits_out, int* __restrict__ tok_e,
    float* __restrict__ tok_w, int* __restrict__ ctrl) {
  const int lane = threadIdx.x & 63;
  const int t = blockIdx.x * 4 + (threadIdx.x >> 6);
  const float4* xp = (const float4*)(x + (size_t)t * Hh + lane * 16);
  float4 x0 = xp[0], x1 = xp[1], x2 = xp[2], x3 = xp[3];
  float lg[Ee];
#pragma unroll
  for (int e = 0; e < Ee; ++e) {
    const float4* gp = (const float4*)(gw + e * Hh + lane * 16);
    float4 g0 = gp[0], g1 = gp[1], g2 = gp[2], g3 = gp[3];
    float s = x0.x*g0.x + x0.y*g0.y + x0.z*g0.z + x0.w*g0.w
            + x1.x*g1.x + x1.y*g1.y + x1.z*g1.z + x1.w*g1.w
            + x2.x*g2.x + x2.y*g2.y + x2.z*g2.z + x2.w*g2.w
            + x3.x*g3.x + x3.y*g3.y + x3.z*g3.z + x3.w*g3.w;
#pragma unroll
    for (int o = 32; o; o >>= 1) s += __shfl_xor(s, o);
    lg[e] = s;
  }
  if (lane == 0) {
    float m = lg[0];
#pragma unroll
    for (int e = 1; e < Ee; ++e) m = fmaxf(m, lg[e]);
    float p[Ee];
#pragma unroll
    for (int e = 0; e < Ee; ++e) p[e] = expf(lg[e] - m);
    int a0 = 0;
#pragma unroll
    for (int e = 1; e < Ee; ++e) if (p[e] > p[a0]) a0 = e;
    int a1 = (a0 == 0) ? 1 : 0;
#pragma unroll
    for (int e = 0; e < Ee; ++e) if (e != a0 && p[e] > p[a1]) a1 = e;
    float rs = p[a0] + p[a1];
    float w0 = p[a0] / rs, w1 = p[a1] / rs;
#pragma unroll
    for (int e = 0; e < Ee; ++e) logits_out[(size_t)t * Ee + e] = lg[e];
    tok_e[t * 2] = a0; tok_e[t * 2 + 1] = a1;
    tok_w[t * 2] = w0; tok_w[t * 2 + 1] = w1;
    atomicAdd(&ctrl[a0], 1); atomicAdd(&ctrl[a1], 1);
  }
}

__global__ void offsets_kernel(int* ctrl) {
  if (threadIdx.x == 0) {
    int acc = 0;
    for (int e = 0; e < Ee; ++e) {
      ctrl[16 + e] = acc;
      acc += ((ctrl[e] + 127) >> 7) << 7;
    }
    ctrl[16 + Ee] = acc;
  }
}

__global__ __launch_bounds__(512) void assign_kernel(
    int* ctrl, const int* __restrict__ tok_e, const float* __restrict__ tok_w,
    int* __restrict__ rowmap, float* __restrict__ roww) {
  int i = blockIdx.x * 512 + threadIdx.x;
  if (i < 2 * Tt) {
    int e = tok_e[i];
    int pos = atomicAdd(&ctrl[8 + e], 1);
    int r = ctrl[16 + e] + pos;
    rowmap[r] = i >> 1;
    roww[r] = tok_w[i];
  }
  if (i < Ee * 128) {
    int e = i >> 7, pd = i & 127;
    int o = ctrl[16 + e], o1 = ctrl[16 + e + 1], c = ctrl[e];
    int r = o + c + pd;
    if (r < o1) { rowmap[r] = -1; roww[r] = 0.f; }
  }
}

// ---------------- gather x rows -> bf16 Xg ----------------
__global__ __launch_bounds__(128) void gather_kernel(
    const float* __restrict__ x, const int* __restrict__ ctrl,
    const int* __restrict__ rowmap, unsigned short* __restrict__ Xg) {
  int r = blockIdx.x;
  if (r >= ctrl[16 + Ee]) return;
  int t = rowmap[r];
  int j = threadIdx.x;
  uint4 v = make_uint4(0u, 0u, 0u, 0u);
  if (t >= 0) {
    const float4* xp = (const float4*)(x + (size_t)t * Hh + j * 8);
    float4 a = xp[0], b = xp[1];
    v.x = (unsigned)f2bf(a.x) | ((unsigned)f2bf(a.y) << 16);
    v.y = (unsigned)f2bf(a.z) | ((unsigned)f2bf(a.w) << 16);
    v.z = (unsigned)f2bf(b.x) | ((unsigned)f2bf(b.y) << 16);
    v.w = (unsigned)f2bf(b.z) | ((unsigned)f2bf(b.w) << 16);
  }
  *(uint4*)(Xg + (size_t)r * Hh + j * 8) = v;
}

// -------- transpose-convert, bank-analyzed rewrite --------
// LDS T[c][r] 64x64 bf16, elem (c,r) at byte c*128 + ((2r) ^ M(c)),
// M(c) = ((c&7) ^ ((c>>3)&7)) << 4.
// Writes: per thread 4x ds_write_b64 (4 r's per c). Reads: b128, quad-group spread.
__global__ __launch_bounds__(256) void tc_all(
    const float* __restrict__ w1, const float* __restrict__ w3,
    const float* __restrict__ w2, unsigned short* __restrict__ w1T,
    unsigned short* __restrict__ w3T, unsigned short* __restrict__ w2T) {
  __shared__ alignas(16) char sT[64 * 128];
  const int z = blockIdx.z;
  const float* in = (z == 0) ? w1 : (z == 1) ? w3 : w2;
  unsigned short* out = (z == 0) ? w1T : (z == 1) ? w3T : w2T;
  const int C = (z == 2) ? Hh : Ff;
  const int tiles_c = (z == 2) ? 16 : 56;
  const int R = (z == 2) ? Ff : Hh;
  const int e = blockIdx.y;
  const int tr = blockIdx.x / tiles_c, tc = blockIdx.x % tiles_c;
  const int r0 = tr * 64, c0 = tc * 64;
  const float* src = in + (size_t)e * R * C;
  unsigned short* dst = out + (size_t)e * R * C;
  const int t = threadIdx.x;

  // load 4x4 fp32 block: rows rb..rb+3, cols col4..col4+3
  const int col4 = (t & 15) * 4, rb = (t >> 4) * 4;
  float4 v0 = *(const float4*)(src + (size_t)(r0 + rb + 0) * C + c0 + col4);
  float4 v1 = *(const float4*)(src + (size_t)(r0 + rb + 1) * C + c0 + col4);
  float4 v2 = *(const float4*)(src + (size_t)(r0 + rb + 2) * C + c0 + col4);
  float4 v3 = *(const float4*)(src + (size_t)(r0 + rb + 3) * C + c0 + col4);
  const float* a0 = (const float*)&v0;
  const float* a1 = (const float*)&v1;
  const float* a2 = (const float*)&v2;
  const float* a3 = (const float*)&v3;
#pragma unroll
  for (int j = 0; j < 4; ++j) {
    int c = col4 + j;
    int M = (((c & 7) ^ ((c >> 3) & 7)) << 4);
    uint2 val;
    val.x = (unsigned)f2bf(a0[j]) | ((unsigned)f2bf(a1[j]) << 16);
    val.y = (unsigned)f2bf(a2[j]) | ((unsigned)f2bf(a3[j]) << 16);
    *(uint2*)(sT + c * 128 + ((rb * 2) ^ M)) = val;
  }
  __syncthreads();
  const int lane = t & 63, wv = t >> 6;
  const int h8 = lane >> 3;
#pragma unroll
  for (int p = 0; p < 2; ++p) {
    int c = p * 32 + wv * 8 + (lane & 7);
    int M = (((c & 7) ^ ((c >> 3) & 7)) << 4);
    uint4 q = *(const uint4*)(sT + c * 128 + ((h8 * 16) ^ M));
    *(uint4*)(dst + (size_t)(c0 + c) * R + r0 + h8 * 8) = q;
  }
}

// ---------- stage A GEMM: 512 thr, BM=BN=128, BK=32, counted-vmcnt dbuf ----------
__global__ __launch_bounds__(512, 4) void ffn13_bf16(
    const unsigned short* __restrict__ Xg, const unsigned short* __restrict__ w1T,
    const unsigned short* __restrict__ w3T, const int* __restrict__ ctrl,
    unsigned short* __restrict__ G) {
  __shared__ alignas(16) char sA[2][8192], sB1[2][8192], sB3[2][8192];
  int lin = blockIdx.y * 28 + blockIdx.x;
  int wg = (lin & 7) * 448 + (lin >> 3);
  int bx = wg % 28, by = wg / 28;
  const int e = by >> 4, mt = by & 15;
  const int off0 = ctrl[16 + e], off1 = ctrl[16 + e + 1];
  const int row0 = off0 + mt * 128;
  if (row0 >= off1) return;
  const int n0 = bx * 128;
  const int tid = threadIdx.x, lane = tid & 63, wv = tid >> 6;
  const int wr = wv >> 2, wc = wv & 3;
  const unsigned short* w1e = w1T + (size_t)e * Ff * Hh;
  const unsigned short* w3e = w3T + (size_t)e * Ff * Hh;
  f32x4 acc1[4][2] = {};
  f32x4 acc3[4][2] = {};
  const int srow = wv * 16 + (lane >> 2);
  const int sgc = (lane & 3) ^ ((lane >> 3) & 3);
  const int swb = wv * 16;

  const unsigned short* gA = Xg + (size_t)(row0 + srow) * Hh + sgc * 8;
  const unsigned short* gB1 = w1e + (size_t)(n0 + srow) * Hh + sgc * 8;
  const unsigned short* gB3 = w3e + (size_t)(n0 + srow) * Hh + sgc * 8;

  // prologue: stage tile 0 into buf 0
  gload_lds16(gA, sA[0] + swb * 64);
  gload_lds16(gB1, sB1[0] + swb * 64);
  gload_lds16(gB3, sB3[0] + swb * 64);

  for (int it = 0; it < 32; ++it) {
    int cur = it & 1;
    int nx = it + 1; if (nx == 32) nx = 0;
    size_t so = (size_t)nx * 32;
    gload_lds16(gA + so, sA[cur ^ 1] + swb * 64);
    gload_lds16(gB1 + so, sB1[cur ^ 1] + swb * 64);
    gload_lds16(gB3 + so, sB3[cur ^ 1] + swb * 64);
    asm volatile("s_waitcnt vmcnt(3)" ::: "memory");
    __builtin_amdgcn_s_barrier();
    __builtin_amdgcn_sched_barrier(0);
    const int gc = lane >> 4;
    bf16x8 af[4];
#pragma unroll
    for (int mi = 0; mi < 4; ++mi)
      af[mi] = frg(sA[cur], wr * 64 + mi * 16 + (lane & 15), gc);
    __builtin_amdgcn_s_setprio(1);
#pragma unroll
    for (int ni = 0; ni < 2; ++ni) {
      bf16x8 b1 = frg(sB1[cur], wc * 32 + ni * 16 + (lane & 15), gc);
      bf16x8 b3 = frg(sB3[cur], wc * 32 + ni * 16 + (lane & 15), gc);
#pragma unroll
      for (int mi = 0; mi < 4; ++mi) {
        acc1[mi][ni] = __builtin_amdgcn_mfma_f32_16x16x32_bf16(af[mi], b1, acc1[mi][ni], 0, 0, 0);
        acc3[mi][ni] = __builtin_amdgcn_mfma_f32_16x16x32_bf16(af[mi], b3, acc3[mi][ni], 0, 0, 0);
      }
    }
    __builtin_amdgcn_s_setprio(0);
    __builtin_amdgcn_sched_barrier(0);
    __builtin_amdgcn_s_barrier();
  }
  asm volatile("s_waitcnt vmcnt(0)" ::: "memory");
  const int rb = wr * 64 + 4 * (lane >> 4), cb = wc * 32 + (lane & 15);
#pragma unroll
  for (int mi = 0; mi < 4; ++mi)
#pragma unroll
    for (int ni = 0; ni < 2; ++ni)
#pragma unroll
      for (int r = 0; r < 4; ++r) {
        float h1 = acc1[mi][ni][r], h3 = acc3[mi][ni][r];
        float gv = h1 / (1.f + __expf(-h1)) * h3;
        G[(size_t)(row0 + rb + mi * 16 + r) * Ff + n0 + cb + ni * 16] = f2bf(gv);
      }
}

// ---------- stage B GEMM: 256 thr, BM=BN=128, BK=32, K-split x4, counted-vmcnt ----------
__global__ __launch_bounds__(256, 4) void ffn2_bf16(
    const unsigned short* __restrict__ G, const unsigned short* __restrict__ w2T,
    const int* __restrict__ ctrl, const int* __restrict__ rowmap,
    const float* __restrict__ roww, float* __restrict__ out) {
  __shared__ alignas(16) char sA[2][8192], sB[2][8192];
  int lin = blockIdx.y * 8 + blockIdx.x;
  int wg = (lin & 7) * 128 + (lin >> 3);
  int bx = wg % 8, by = wg / 8;
  const int e = by >> 4, mt = by & 15;
  const int off0 = ctrl[16 + e], off1 = ctrl[16 + e + 1];
  const int row0 = off0 + mt * 128;
  if (row0 >= off1) return;
  const int n0 = bx * 128;
  const int kb = blockIdx.z * (Ff / 4);
  const int tid = threadIdx.x, lane = tid & 63, wv = tid >> 6;
  const int wr = wv >> 1, wc = wv & 1;
  const unsigned short* w2e = w2T + (size_t)e * Ff * Hh;
  f32x4 acc[4][4] = {};
  const int sl = lane >> 2;
  const int sgc = (lane & 3) ^ ((lane >> 3) & 3);

  const unsigned short* gA0 = G + (size_t)(row0 + wv * 16 + sl) * Ff + kb + sgc * 8;
  const unsigned short* gA1 = G + (size_t)(row0 + 64 + wv * 16 + sl) * Ff + kb + sgc * 8;
  const unsigned short* gB0 = w2e + (size_t)(n0 + wv * 16 + sl) * Ff + kb + sgc * 8;
  const unsigned short* gB1 = w2e + (size_t)(n0 + 64 + wv * 16 + sl) * Ff + kb + sgc * 8;

  // prologue
  gload_lds16(gA0, sA[0] + (wv * 16) * 64);
  gload_lds16(gA1, sA[0] + (wv * 16 + 64) * 64);
  gload_lds16(gB0, sB[0] + (wv * 16) * 64);
  gload_lds16(gB1, sB[0] + (wv * 16 + 64) * 64);

  for (int it = 0; it < 28; ++it) {
    int cur = it & 1;
    int nx = it + 1; if (nx == 28) nx = 0;
    size_t so = (size_t)nx * 32;
    gload_lds16(gA0 + so, sA[cur ^ 1] + (wv * 16) * 64);
    gload_lds16(gA1 + so, sA[cur ^ 1] + (wv * 16 + 64) * 64);
    gload_lds16(gB0 + so, sB[cur ^ 1] + (wv * 16) * 64);
    gload_lds16(gB1 + so, sB[cur ^ 1] + (wv * 16 + 64) * 64);
    asm volatile("s_waitcnt vmcnt(4)" ::: "memory");
    __builtin_amdgcn_s_barrier();
    __builtin_amdgcn_sched_barrier(0);
    const int gc = lane >> 4;
    bf16x8 af[4];
#pragma unroll
    for (int mi = 0; mi < 4; ++mi)
      af[mi] = frg(sA[cur], wr * 64 + mi * 16 + (lane & 15), gc);
    __builtin_amdgcn_s_setprio(1);
#pragma unroll
    for (int ni = 0; ni < 4; ++ni) {
      bf16x8 b = frg(sB[cur], wc * 64 + ni * 16 + (lane & 15), gc);
#pragma unroll
      for (int mi = 0; mi < 4; ++mi)
        acc[mi][ni] = __builtin_amdgcn_mfma_f32_16x16x32_bf16(af[mi], b, acc[mi][ni], 0, 0, 0);
    }
    __builtin_amdgcn_s_setprio(0);
    __builtin_amdgcn_sched_barrier(0);
    __builtin_amdgcn_s_barrier();
  }
  asm volatile("s_waitcnt vmcnt(0)" ::: "memory");
  const int rb = wr * 64 + 4 * (lane >> 4), cb = wc * 64 + (lane & 15);
#pragma unroll
  for (int mi = 0; mi < 4; ++mi)
#pragma unroll
    for (int r = 0; r < 4; ++r) {
      int grow = row0 + rb + mi * 16 + r;
      int t = rowmap[grow];
      if (t < 0) continue;
      float wgt = roww[grow];
#pragma unroll
      for (int ni = 0; ni < 4; ++ni)
        atomicAdd(&out[(size_t)t * Hh + n0 + cb + ni * 16], wgt * acc[mi][ni][r]);
    }
}

extern "C" void kernel_launch(void* const* d_in, const int* in_sizes, int n_in,
                              void* d_out, int out_size, void* d_ws, size_t ws_size,
                              hipStream_t stream) {
  const float* x  = (const float*)d_in[0];
  const float* gw = (const float*)d_in[1];
  const float* w1 = (const float*)d_in[2];
  const float* w3 = (const float*)d_in[3];
  const float* w2 = (const float*)d_in[4];
  float* out = (float*)d_out;
  float* logits = out + (size_t)Tt * Hh;
  char* ws = (char*)d_ws;
  int* ctrl = (int*)(ws + OFF_CTRL);
  int* tok_e = (int*)(ws + OFF_TOKE);
  float* tok_w = (float*)(ws + OFF_TOKW);
  int* rowmap = (int*)(ws + OFF_ROWMAP);
  float* roww = (float*)(ws + OFF_ROWW);
  unsigned short* Xg = (unsigned short*)(ws + OFF_XG);
  unsigned short* G  = (unsigned short*)(ws + OFF_G);
  unsigned short* w1T = (unsigned short*)(ws + OFF_W1T);
  unsigned short* w3T = (unsigned short*)(ws + OFF_W3T);
  unsigned short* w2T = (unsigned short*)(ws + OFF_W2T);

  hipMemsetAsync(ctrl, 0, 256, stream);
  hipMemsetAsync(out, 0, (size_t)Tt * Hh * sizeof(float), stream);
  router_kernel<<<Tt / 4, 256, 0, stream>>>(x, gw, logits, tok_e, tok_w, ctrl);
  offsets_kernel<<<1, 64, 0, stream>>>(ctrl);
  assign_kernel<<<8, 512, 0, stream>>>(ctrl, tok_e, tok_w, rowmap, roww);
  gather_kernel<<<ROWS_CAP, 128, 0, stream>>>(x, ctrl, rowmap, Xg);
  tc_all<<<dim3(896, Ee, 3), 256, 0, stream>>>(w1, w3, w2, w1T, w3T, w2T);
  ffn13_bf16<<<dim3(28, Ee * 16), 512, 0, stream>>>(Xg, w1T, w3T, ctrl, G);
  ffn2_bf16<<<dim3(8, Ee * 16, 4), 256, 0, stream>>>(G, w2T, ctrl, rowmap, roww, out);
}

// Round 5
// 344.824 us; speedup vs baseline: 1.4915x; 1.0647x over previous
//
#include <hip/hip_runtime.h>
#include <cstdint>
#include <cstddef>

#define Tt 2048
#define Hh 1024
#define Ff 3584
#define Ee 8
#define ROWS_CAP 5120

#define OFF_CTRL   0u
#define OFF_TOKE   256u
#define OFF_TOKW   (256u + 16384u)
#define OFF_ROWMAP (256u + 32768u)
#define OFF_ROWW   (256u + 32768u + 20480u)
#define OFF_XG     (1ull << 20)
#define OFF_G      (12ull << 20)

typedef __attribute__((ext_vector_type(8))) short bf16x8;
typedef __attribute__((ext_vector_type(4))) float f32x4;

__device__ __forceinline__ unsigned short f2bf(float f) {
  unsigned int u = __float_as_uint(f);
  u += 0x7fffu + ((u >> 16) & 1u);
  return (unsigned short)(u >> 16);
}

__device__ __forceinline__ unsigned pkbf(float a, float b) {
  unsigned r;
  asm("v_cvt_pk_bf16_f32 %0, %1, %2" : "=v"(r) : "v"(a), "v"(b));
  return r;
}

__device__ __forceinline__ void gload_lds16(const void* g, void* l) {
  auto gp = (const __attribute__((address_space(1))) char*)(uintptr_t)g;
  auto lp = (__attribute__((address_space(3))) char*)(uintptr_t)l;
  __builtin_amdgcn_global_load_lds(gp, lp, 16, 0, 0);
}

// LDS tile: 128 rows x 32 k bf16 (64 B/row); chunk gc at pos = gc ^ ((row>>1)&3).
__device__ __forceinline__ bf16x8 frg(const char* lds, int row, int gc) {
  return *(const bf16x8*)(lds + row * 64 + ((gc ^ ((row >> 1) & 3)) * 16));
}

// ---------------- router ----------------
__global__ __launch_bounds__(256) void router_kernel(
    const float* __restrict__ x, const float* __restrict__ gw,
    float* __restrict__ logits_out, int* __restrict__ tok_e,
    float* __restrict__ tok_w, int* __restrict__ ctrl) {
  const int lane = threadIdx.x & 63;
  const int t = blockIdx.x * 4 + (threadIdx.x >> 6);
  const float4* xp = (const float4*)(x + (size_t)t * Hh + lane * 16);
  float4 x0 = xp[0], x1 = xp[1], x2 = xp[2], x3 = xp[3];
  float lg[Ee];
#pragma unroll
  for (int e = 0; e < Ee; ++e) {
    const float4* gp = (const float4*)(gw + e * Hh + lane * 16);
    float4 g0 = gp[0], g1 = gp[1], g2 = gp[2], g3 = gp[3];
    float s = x0.x*g0.x + x0.y*g0.y + x0.z*g0.z + x0.w*g0.w
            + x1.x*g1.x + x1.y*g1.y + x1.z*g1.z + x1.w*g1.w
            + x2.x*g2.x + x2.y*g2.y + x2.z*g2.z + x2.w*g2.w
            + x3.x*g3.x + x3.y*g3.y + x3.z*g3.z + x3.w*g3.w;
#pragma unroll
    for (int o = 32; o; o >>= 1) s += __shfl_xor(s, o);
    lg[e] = s;
  }
  if (lane == 0) {
    float m = lg[0];
#pragma unroll
    for (int e = 1; e < Ee; ++e) m = fmaxf(m, lg[e]);
    float p[Ee];
#pragma unroll
    for (int e = 0; e < Ee; ++e) p[e] = expf(lg[e] - m);
    int a0 = 0;
#pragma unroll
    for (int e = 1; e < Ee; ++e) if (p[e] > p[a0]) a0 = e;
    int a1 = (a0 == 0) ? 1 : 0;
#pragma unroll
    for (int e = 0; e < Ee; ++e) if (e != a0 && p[e] > p[a1]) a1 = e;
    float rs = p[a0] + p[a1];
    float w0 = p[a0] / rs, w1 = p[a1] / rs;
#pragma unroll
    for (int e = 0; e < Ee; ++e) logits_out[(size_t)t * Ee + e] = lg[e];
    tok_e[t * 2] = a0; tok_e[t * 2 + 1] = a1;
    tok_w[t * 2] = w0; tok_w[t * 2 + 1] = w1;
    atomicAdd(&ctrl[a0], 1); atomicAdd(&ctrl[a1], 1);
  }
}

__global__ void offsets_kernel(int* ctrl) {
  if (threadIdx.x == 0) {
    int acc = 0;
    for (int e = 0; e < Ee; ++e) {
      ctrl[16 + e] = acc;
      acc += ((ctrl[e] + 127) >> 7) << 7;
    }
    ctrl[16 + Ee] = acc;
  }
}

__global__ __launch_bounds__(512) void assign_kernel(
    int* ctrl, const int* __restrict__ tok_e, const float* __restrict__ tok_w,
    int* __restrict__ rowmap, float* __restrict__ roww) {
  int i = blockIdx.x * 512 + threadIdx.x;
  if (i < 2 * Tt) {
    int e = tok_e[i];
    int pos = atomicAdd(&ctrl[8 + e], 1);
    int r = ctrl[16 + e] + pos;
    rowmap[r] = i >> 1;
    roww[r] = tok_w[i];
  }
  if (i < Ee * 128) {
    int e = i >> 7, pd = i & 127;
    int o = ctrl[16 + e], o1 = ctrl[16 + e + 1], c = ctrl[e];
    int r = o + c + pd;
    if (r < o1) { rowmap[r] = -1; roww[r] = 0.f; }
  }
}

// ---------------- gather x rows -> bf16 Xg ----------------
__global__ __launch_bounds__(128) void gather_kernel(
    const float* __restrict__ x, const int* __restrict__ ctrl,
    const int* __restrict__ rowmap, unsigned short* __restrict__ Xg) {
  int r = blockIdx.x;
  if (r >= ctrl[16 + Ee]) return;
  int t = rowmap[r];
  int j = threadIdx.x;
  uint4 v = make_uint4(0u, 0u, 0u, 0u);
  if (t >= 0) {
    const float4* xp = (const float4*)(x + (size_t)t * Hh + j * 8);
    float4 a = xp[0], b = xp[1];
    v.x = (unsigned)f2bf(a.x) | ((unsigned)f2bf(a.y) << 16);
    v.y = (unsigned)f2bf(a.z) | ((unsigned)f2bf(a.w) << 16);
    v.z = (unsigned)f2bf(b.x) | ((unsigned)f2bf(b.y) << 16);
    v.w = (unsigned)f2bf(b.z) | ((unsigned)f2bf(b.w) << 16);
  }
  *(uint4*)(Xg + (size_t)r * Hh + j * 8) = v;
}

// ---------- stage A fused: G = silu(Xg@w1^T)*(Xg@w3^T), fp32 weights converted in-staging ----------
// BM=BN=128, BK=32, 512 thr (8 waves 2x4), dbuf, T14 issue-early/write-late.
__global__ __launch_bounds__(512, 4) void ffn13_fused(
    const unsigned short* __restrict__ Xg, const float* __restrict__ w1,
    const float* __restrict__ w3, const int* __restrict__ ctrl,
    unsigned short* __restrict__ G) {
  __shared__ alignas(16) char sA[2][8192], sB1[2][8192], sB3[2][8192];
  int lin = blockIdx.y * 28 + blockIdx.x;          // 3584 blocks, %8==0
  int wg = (lin & 7) * 448 + (lin >> 3);
  int bx = wg % 28, by = wg / 28;
  const int e = by >> 4, mt = by & 15;
  const int off0 = ctrl[16 + e], off1 = ctrl[16 + e + 1];
  const int row0 = off0 + mt * 128;
  if (row0 >= off1) return;
  const int n0 = bx * 128;
  const int tid = threadIdx.x, lane = tid & 63, wv = tid >> 6;
  const int wr = wv >> 2, wc = wv & 3;             // wave tile 64x32
  const float* w1e = w1 + (size_t)e * Hh * Ff;
  const float* w3e = w3 + (size_t)e * Hh * Ff;
  f32x4 acc1[4][2] = {};
  f32x4 acc3[4][2] = {};
  // A staging (bf16, global_load_lds with pre-swizzled source)
  const int srow = wv * 16 + (lane >> 2);
  const int sgc = (lane & 3) ^ ((lane >> 3) & 3);
  const unsigned short* gA = Xg + (size_t)(row0 + srow) * Hh + sgc * 8;
  // B staging (fp32 -> bf16 convert, swizzled b128 LDS write)
  const int bn = tid & 127, bkq = tid >> 7;        // n-row, k-chunk(8)
  const int posB = bkq ^ ((bn >> 1) & 3);
  const int wofB = bn * 64 + posB * 16;
  const float* pB1 = w1e + (size_t)(bkq * 8) * Ff + n0 + bn;
  const float* pB3 = w3e + (size_t)(bkq * 8) * Ff + n0 + bn;
  float r1[8], r3[8];

  // prologue: stage k-tile 0 into buf 0
#pragma unroll
  for (int i = 0; i < 8; ++i) r1[i] = pB1[(size_t)i * Ff];
#pragma unroll
  for (int i = 0; i < 8; ++i) r3[i] = pB3[(size_t)i * Ff];
  gload_lds16(gA, sA[0] + wv * 1024);
  {
    uint4 q;
    q.x = pkbf(r1[0], r1[1]); q.y = pkbf(r1[2], r1[3]);
    q.z = pkbf(r1[4], r1[5]); q.w = pkbf(r1[6], r1[7]);
    *(uint4*)(sB1[0] + wofB) = q;
    q.x = pkbf(r3[0], r3[1]); q.y = pkbf(r3[2], r3[3]);
    q.z = pkbf(r3[4], r3[5]); q.w = pkbf(r3[6], r3[7]);
    *(uint4*)(sB3[0] + wofB) = q;
  }
  __syncthreads();

  for (int it = 0; it < 32; ++it) {
    const int cur = it & 1;
    if (it < 31) {
      const size_t ko = (size_t)(it + 1) * 32;
      gload_lds16(gA + ko, sA[cur ^ 1] + wv * 1024);
      const float* p1 = pB1 + ko * Ff;
      const float* p3 = pB3 + ko * Ff;
#pragma unroll
      for (int i = 0; i < 8; ++i) r1[i] = p1[(size_t)i * Ff];
#pragma unroll
      for (int i = 0; i < 8; ++i) r3[i] = p3[(size_t)i * Ff];
    }
    const int gc = lane >> 4;
    bf16x8 af[4];
#pragma unroll
    for (int mi = 0; mi < 4; ++mi)
      af[mi] = frg(sA[cur], wr * 64 + mi * 16 + (lane & 15), gc);
    __builtin_amdgcn_s_setprio(1);
#pragma unroll
    for (int ni = 0; ni < 2; ++ni) {
      bf16x8 b1 = frg(sB1[cur], wc * 32 + ni * 16 + (lane & 15), gc);
      bf16x8 b3 = frg(sB3[cur], wc * 32 + ni * 16 + (lane & 15), gc);
#pragma unroll
      for (int mi = 0; mi < 4; ++mi) {
        acc1[mi][ni] = __builtin_amdgcn_mfma_f32_16x16x32_bf16(af[mi], b1, acc1[mi][ni], 0, 0, 0);
        acc3[mi][ni] = __builtin_amdgcn_mfma_f32_16x16x32_bf16(af[mi], b3, acc3[mi][ni], 0, 0, 0);
      }
    }
    __builtin_amdgcn_s_setprio(0);
    if (it < 31) {
      uint4 q;
      q.x = pkbf(r1[0], r1[1]); q.y = pkbf(r1[2], r1[3]);
      q.z = pkbf(r1[4], r1[5]); q.w = pkbf(r1[6], r1[7]);
      *(uint4*)(sB1[cur ^ 1] + wofB) = q;
      q.x = pkbf(r3[0], r3[1]); q.y = pkbf(r3[2], r3[3]);
      q.z = pkbf(r3[4], r3[5]); q.w = pkbf(r3[6], r3[7]);
      *(uint4*)(sB3[cur ^ 1] + wofB) = q;
    }
    __syncthreads();
  }
  const int rb = wr * 64 + 4 * (lane >> 4), cb = wc * 32 + (lane & 15);
#pragma unroll
  for (int mi = 0; mi < 4; ++mi)
#pragma unroll
    for (int ni = 0; ni < 2; ++ni)
#pragma unroll
      for (int r = 0; r < 4; ++r) {
        float h1 = acc1[mi][ni][r], h3 = acc3[mi][ni][r];
        float gv = h1 / (1.f + __expf(-h1)) * h3;
        G[(size_t)(row0 + rb + mi * 16 + r) * Ff + n0 + cb + ni * 16] = f2bf(gv);
      }
}

// ---------- stage B fused: out[t] += w * (G@w2^T), fp32 w2 converted in-staging ----------
// BM=BN=128, BK=32, 512 thr, K=3584 (112 iters), no K-split.
__global__ __launch_bounds__(512, 4) void ffn2_fused(
    const unsigned short* __restrict__ G, const float* __restrict__ w2,
    const int* __restrict__ ctrl, const int* __restrict__ rowmap,
    const float* __restrict__ roww, float* __restrict__ out) {
  __shared__ alignas(16) char sA[2][8192], sB[2][8192];
  int lin = blockIdx.y * 8 + blockIdx.x;           // 1024 blocks
  int wg = (lin & 7) * 128 + (lin >> 3);
  int bx = wg % 8, by = wg / 8;
  const int e = by >> 4, mt = by & 15;
  const int off0 = ctrl[16 + e], off1 = ctrl[16 + e + 1];
  const int row0 = off0 + mt * 128;
  if (row0 >= off1) return;
  const int n0 = bx * 128;
  const int tid = threadIdx.x, lane = tid & 63, wv = tid >> 6;
  const int wr = wv >> 2, wc = wv & 3;             // wave tile 64x32
  const float* w2e = w2 + (size_t)e * Ff * Hh;
  f32x4 acc[4][2] = {};
  const int srow = wv * 16 + (lane >> 2);
  const int sgc = (lane & 3) ^ ((lane >> 3) & 3);
  const unsigned short* gA = G + (size_t)(row0 + srow) * Ff + sgc * 8;
  const int bn = tid & 127, bkq = tid >> 7;
  const int posB = bkq ^ ((bn >> 1) & 3);
  const int wofB = bn * 64 + posB * 16;
  const float* pB = w2e + (size_t)(bkq * 8) * Hh + n0 + bn;
  float r2[8];

  // prologue
#pragma unroll
  for (int i = 0; i < 8; ++i) r2[i] = pB[(size_t)i * Hh];
  gload_lds16(gA, sA[0] + wv * 1024);
  {
    uint4 q;
    q.x = pkbf(r2[0], r2[1]); q.y = pkbf(r2[2], r2[3]);
    q.z = pkbf(r2[4], r2[5]); q.w = pkbf(r2[6], r2[7]);
    *(uint4*)(sB[0] + wofB) = q;
  }
  __syncthreads();

  for (int it = 0; it < 112; ++it) {
    const int cur = it & 1;
    if (it < 111) {
      const size_t ko = (size_t)(it + 1) * 32;
      gload_lds16(gA + ko, sA[cur ^ 1] + wv * 1024);
      const float* p2 = pB + ko * Hh;
#pragma unroll
      for (int i = 0; i < 8; ++i) r2[i] = p2[(size_t)i * Hh];
    }
    const int gc = lane >> 4;
    bf16x8 af[4];
#pragma unroll
    for (int mi = 0; mi < 4; ++mi)
      af[mi] = frg(sA[cur], wr * 64 + mi * 16 + (lane & 15), gc);
    __builtin_amdgcn_s_setprio(1);
#pragma unroll
    for (int ni = 0; ni < 2; ++ni) {
      bf16x8 b = frg(sB[cur], wc * 32 + ni * 16 + (lane & 15), gc);
#pragma unroll
      for (int mi = 0; mi < 4; ++mi)
        acc[mi][ni] = __builtin_amdgcn_mfma_f32_16x16x32_bf16(af[mi], b, acc[mi][ni], 0, 0, 0);
    }
    __builtin_amdgcn_s_setprio(0);
    if (it < 111) {
      uint4 q;
      q.x = pkbf(r2[0], r2[1]); q.y = pkbf(r2[2], r2[3]);
      q.z = pkbf(r2[4], r2[5]); q.w = pkbf(r2[6], r2[7]);
      *(uint4*)(sB[cur ^ 1] + wofB) = q;
    }
    __syncthreads();
  }
  const int rb = wr * 64 + 4 * (lane >> 4), cb = wc * 32 + (lane & 15);
#pragma unroll
  for (int mi = 0; mi < 4; ++mi)
#pragma unroll
    for (int r = 0; r < 4; ++r) {
      int grow = row0 + rb + mi * 16 + r;
      int t = rowmap[grow];
      if (t < 0) continue;
      float wgt = roww[grow];
#pragma unroll
      for (int ni = 0; ni < 2; ++ni)
        atomicAdd(&out[(size_t)t * Hh + n0 + cb + ni * 16], wgt * acc[mi][ni][r]);
    }
}

extern "C" void kernel_launch(void* const* d_in, const int* in_sizes, int n_in,
                              void* d_out, int out_size, void* d_ws, size_t ws_size,
                              hipStream_t stream) {
  const float* x  = (const float*)d_in[0];
  const float* gw = (const float*)d_in[1];
  const float* w1 = (const float*)d_in[2];
  const float* w3 = (const float*)d_in[3];
  const float* w2 = (const float*)d_in[4];
  float* out = (float*)d_out;
  float* logits = out + (size_t)Tt * Hh;
  char* ws = (char*)d_ws;
  int* ctrl = (int*)(ws + OFF_CTRL);
  int* tok_e = (int*)(ws + OFF_TOKE);
  float* tok_w = (float*)(ws + OFF_TOKW);
  int* rowmap = (int*)(ws + OFF_ROWMAP);
  float* roww = (float*)(ws + OFF_ROWW);
  unsigned short* Xg = (unsigned short*)(ws + OFF_XG);
  unsigned short* G  = (unsigned short*)(ws + OFF_G);

  hipMemsetAsync(ctrl, 0, 256, stream);
  hipMemsetAsync(out, 0, (size_t)Tt * Hh * sizeof(float), stream);
  router_kernel<<<Tt / 4, 256, 0, stream>>>(x, gw, logits, tok_e, tok_w, ctrl);
  offsets_kernel<<<1, 64, 0, stream>>>(ctrl);
  assign_kernel<<<8, 512, 0, stream>>>(ctrl, tok_e, tok_w, rowmap, roww);
  gather_kernel<<<ROWS_CAP, 128, 0, stream>>>(x, ctrl, rowmap, Xg);
  ffn13_fused<<<dim3(28, Ee * 16), 512, 0, stream>>>(Xg, w1, w3, ctrl, G);
  ffn2_fused<<<dim3(8, Ee * 16), 512, 0, stream>>>(G, w2, ctrl, rowmap, roww, out);
}

// Round 6
// 332.971 us; speedup vs baseline: 1.5446x; 1.0356x over previous
//
#include <hip/hip_runtime.h>
#include <cstdint>
#include <cstddef>

#define Tt 2048
#define Hh 1024
#define Ff 3584
#define Ee 8
#define ROWS_CAP 5120

#define OFF_CTRL   0u
#define OFF_TOKE   256u
#define OFF_TOKW   (256u + 16384u)
#define OFF_ROWMAP (256u + 32768u)
#define OFF_ROWW   (256u + 32768u + 20480u)
#define OFF_XG     (1ull << 20)
#define OFF_G      (12ull << 20)

typedef __attribute__((ext_vector_type(8))) short bf16x8;
typedef __attribute__((ext_vector_type(4))) float f32x4;

__device__ __forceinline__ unsigned short f2bf(float f) {
  unsigned int u = __float_as_uint(f);
  u += 0x7fffu + ((u >> 16) & 1u);
  return (unsigned short)(u >> 16);
}

__device__ __forceinline__ unsigned pkbf(float a, float b) {
  unsigned r;
  asm("v_cvt_pk_bf16_f32 %0, %1, %2" : "=v"(r) : "v"(a), "v"(b));
  return r;
}

__device__ __forceinline__ void gload_lds16(const void* g, void* l) {
  auto gp = (const __attribute__((address_space(1))) char*)(uintptr_t)g;
  auto lp = (__attribute__((address_space(3))) char*)(uintptr_t)l;
  __builtin_amdgcn_global_load_lds(gp, lp, 16, 0, 0);
}

// LDS tile: 128 rows x 32 k bf16 (64 B/row); chunk gc at pos = gc ^ ((row>>1)&3).
__device__ __forceinline__ bf16x8 frg(const char* lds, int row, int gc) {
  return *(const bf16x8*)(lds + row * 64 + ((gc ^ ((row >> 1) & 3)) * 16));
}

// ---------------- router ----------------
__global__ __launch_bounds__(256) void router_kernel(
    const float* __restrict__ x, const float* __restrict__ gw,
    float* __restrict__ logits_out, int* __restrict__ tok_e,
    float* __restrict__ tok_w, int* __restrict__ ctrl) {
  const int lane = threadIdx.x & 63;
  const int t = blockIdx.x * 4 + (threadIdx.x >> 6);
  const float4* xp = (const float4*)(x + (size_t)t * Hh + lane * 16);
  float4 x0 = xp[0], x1 = xp[1], x2 = xp[2], x3 = xp[3];
  float lg[Ee];
#pragma unroll
  for (int e = 0; e < Ee; ++e) {
    const float4* gp = (const float4*)(gw + e * Hh + lane * 16);
    float4 g0 = gp[0], g1 = gp[1], g2 = gp[2], g3 = gp[3];
    float s = x0.x*g0.x + x0.y*g0.y + x0.z*g0.z + x0.w*g0.w
            + x1.x*g1.x + x1.y*g1.y + x1.z*g1.z + x1.w*g1.w
            + x2.x*g2.x + x2.y*g2.y + x2.z*g2.z + x2.w*g2.w
            + x3.x*g3.x + x3.y*g3.y + x3.z*g3.z + x3.w*g3.w;
#pragma unroll
    for (int o = 32; o; o >>= 1) s += __shfl_xor(s, o);
    lg[e] = s;
  }
  if (lane == 0) {
    float m = lg[0];
#pragma unroll
    for (int e = 1; e < Ee; ++e) m = fmaxf(m, lg[e]);
    float p[Ee];
#pragma unroll
    for (int e = 0; e < Ee; ++e) p[e] = expf(lg[e] - m);
    int a0 = 0;
#pragma unroll
    for (int e = 1; e < Ee; ++e) if (p[e] > p[a0]) a0 = e;
    int a1 = (a0 == 0) ? 1 : 0;
#pragma unroll
    for (int e = 0; e < Ee; ++e) if (e != a0 && p[e] > p[a1]) a1 = e;
    float rs = p[a0] + p[a1];
    float w0 = p[a0] / rs, w1 = p[a1] / rs;
#pragma unroll
    for (int e = 0; e < Ee; ++e) logits_out[(size_t)t * Ee + e] = lg[e];
    tok_e[t * 2] = a0; tok_e[t * 2 + 1] = a1;
    tok_w[t * 2] = w0; tok_w[t * 2 + 1] = w1;
    atomicAdd(&ctrl[a0], 1); atomicAdd(&ctrl[a1], 1);
  }
}

__global__ void offsets_kernel(int* ctrl) {
  if (threadIdx.x == 0) {
    int acc = 0;
    for (int e = 0; e < Ee; ++e) {
      ctrl[16 + e] = acc;
      acc += ((ctrl[e] + 127) >> 7) << 7;
    }
    ctrl[16 + Ee] = acc;
  }
}

__global__ __launch_bounds__(512) void assign_kernel(
    int* ctrl, const int* __restrict__ tok_e, const float* __restrict__ tok_w,
    int* __restrict__ rowmap, float* __restrict__ roww) {
  int i = blockIdx.x * 512 + threadIdx.x;
  if (i < 2 * Tt) {
    int e = tok_e[i];
    int pos = atomicAdd(&ctrl[8 + e], 1);
    int r = ctrl[16 + e] + pos;
    rowmap[r] = i >> 1;
    roww[r] = tok_w[i];
  }
  if (i < Ee * 128) {
    int e = i >> 7, pd = i & 127;
    int o = ctrl[16 + e], o1 = ctrl[16 + e + 1], c = ctrl[e];
    int r = o + c + pd;
    if (r < o1) { rowmap[r] = -1; roww[r] = 0.f; }
  }
}

// ---------------- gather x rows -> bf16 Xg ----------------
__global__ __launch_bounds__(128) void gather_kernel(
    const float* __restrict__ x, const int* __restrict__ ctrl,
    const int* __restrict__ rowmap, unsigned short* __restrict__ Xg) {
  int r = blockIdx.x;
  if (r >= ctrl[16 + Ee]) return;
  int t = rowmap[r];
  int j = threadIdx.x;
  uint4 v = make_uint4(0u, 0u, 0u, 0u);
  if (t >= 0) {
    const float4* xp = (const float4*)(x + (size_t)t * Hh + j * 8);
    float4 a = xp[0], b = xp[1];
    v.x = (unsigned)f2bf(a.x) | ((unsigned)f2bf(a.y) << 16);
    v.y = (unsigned)f2bf(a.z) | ((unsigned)f2bf(a.w) << 16);
    v.z = (unsigned)f2bf(b.x) | ((unsigned)f2bf(b.y) << 16);
    v.w = (unsigned)f2bf(b.z) | ((unsigned)f2bf(b.w) << 16);
  }
  *(uint4*)(Xg + (size_t)r * Hh + j * 8) = v;
}

// ---------- stage A fused: G = silu(Xg@w1^T)*(Xg@w3^T) ----------
// BM=BN=128, BK=32, 512 thr, depth-2 timing reg pipeline + counted-vmcnt barrier.
__global__ __launch_bounds__(512, 4) void ffn13_fused(
    const unsigned short* __restrict__ Xg, const float* __restrict__ w1,
    const float* __restrict__ w3, const int* __restrict__ ctrl,
    unsigned short* __restrict__ G) {
  __shared__ alignas(16) char sA[2][8192], sB1[2][8192], sB3[2][8192];
  // panel->XCD mapping: all mt blocks of panel (e,bx) on one XCD, spaced 8 in dispatch
  int lin = blockIdx.y * 28 + blockIdx.x;          // 0..3583
  int xcd = lin & 7, idx = lin >> 3;               // idx 0..447
  int p = xcd + 8 * (idx >> 4);                    // panel 0..223
  int mt = idx & 15;
  int e = p / 28, bx = p % 28;
  const int off0 = ctrl[16 + e], off1 = ctrl[16 + e + 1];
  const int row0 = off0 + mt * 128;
  if (row0 >= off1) return;
  const int n0 = bx * 128;
  const int tid = threadIdx.x, lane = tid & 63, wv = tid >> 6;
  const int wr = wv >> 2, wc = wv & 3;             // wave tile 64x32
  const float* w1e = w1 + (size_t)e * Hh * Ff;
  const float* w3e = w3 + (size_t)e * Hh * Ff;
  f32x4 acc1[4][2] = {};
  f32x4 acc3[4][2] = {};
  const int srow = wv * 16 + (lane >> 2);
  const int sgc = (lane & 3) ^ ((lane >> 3) & 3);
  const unsigned short* gA = Xg + (size_t)(row0 + srow) * Hh + sgc * 8;
  const int bn = tid & 127, bkq = tid >> 7;
  const int posB = bkq ^ ((bn >> 1) & 3);
  const int wofB = bn * 64 + posB * 16;
  const float* pB1 = w1e + (size_t)(bkq * 8) * Ff + n0 + bn;
  const float* pB3 = w3e + (size_t)(bkq * 8) * Ff + n0 + bn;
  float r1[8], r3[8];

  // ---- prologue: A(0)->sA[0]; B(0)->regs->sB[0]; B(1)->regs ----
  gload_lds16(gA, sA[0] + wv * 1024);
#pragma unroll
  for (int i = 0; i < 8; ++i) r1[i] = pB1[(size_t)i * Ff];
#pragma unroll
  for (int i = 0; i < 8; ++i) r3[i] = pB3[(size_t)i * Ff];
  {
    uint4 q;
    q.x = pkbf(r1[0], r1[1]); q.y = pkbf(r1[2], r1[3]);
    q.z = pkbf(r1[4], r1[5]); q.w = pkbf(r1[6], r1[7]);
    *(uint4*)(sB1[0] + wofB) = q;
    q.x = pkbf(r3[0], r3[1]); q.y = pkbf(r3[2], r3[3]);
    q.z = pkbf(r3[4], r3[5]); q.w = pkbf(r3[6], r3[7]);
    *(uint4*)(sB3[0] + wofB) = q;
  }
#pragma unroll
  for (int i = 0; i < 8; ++i) r1[i] = pB1[(size_t)(32 + i) * Ff];
#pragma unroll
  for (int i = 0; i < 8; ++i) r3[i] = pB3[(size_t)(32 + i) * Ff];
  asm volatile("s_waitcnt vmcnt(16) lgkmcnt(0)" ::: "memory");
  __builtin_amdgcn_s_barrier();
  __builtin_amdgcn_sched_barrier(0);

  for (int it = 0; it < 32; ++it) {
    const int cur = it & 1;
    // (1) issue A(it+1) -> sA[cur^1]
    if (it < 31) gload_lds16(gA + (size_t)(it + 1) * 32, sA[cur ^ 1] + wv * 1024);
    __builtin_amdgcn_sched_barrier(0);
    // (2) write B(it+1) (loaded last iter, fully aged) -> sB[cur^1]
    if (it < 31) {
      uint4 q;
      q.x = pkbf(r1[0], r1[1]); q.y = pkbf(r1[2], r1[3]);
      q.z = pkbf(r1[4], r1[5]); q.w = pkbf(r1[6], r1[7]);
      *(uint4*)(sB1[cur ^ 1] + wofB) = q;
      q.x = pkbf(r3[0], r3[1]); q.y = pkbf(r3[2], r3[3]);
      q.z = pkbf(r3[4], r3[5]); q.w = pkbf(r3[6], r3[7]);
      *(uint4*)(sB3[cur ^ 1] + wofB) = q;
    }
    // (3) issue B(it+2) loads -> regs (stay in flight across the barrier)
    if (it < 30) {
      const float* p1 = pB1 + (size_t)(it + 2) * 32 * Ff;
      const float* p3 = pB3 + (size_t)(it + 2) * 32 * Ff;
#pragma unroll
      for (int i = 0; i < 8; ++i) r1[i] = p1[(size_t)i * Ff];
#pragma unroll
      for (int i = 0; i < 8; ++i) r3[i] = p3[(size_t)i * Ff];
    }
    __builtin_amdgcn_sched_barrier(0);
    // (4) compute on bufs[cur]
    const int gc = lane >> 4;
    bf16x8 af[4];
#pragma unroll
    for (int mi = 0; mi < 4; ++mi)
      af[mi] = frg(sA[cur], wr * 64 + mi * 16 + (lane & 15), gc);
    __builtin_amdgcn_s_setprio(1);
#pragma unroll
    for (int ni = 0; ni < 2; ++ni) {
      bf16x8 b1 = frg(sB1[cur], wc * 32 + ni * 16 + (lane & 15), gc);
      bf16x8 b3 = frg(sB3[cur], wc * 32 + ni * 16 + (lane & 15), gc);
#pragma unroll
      for (int mi = 0; mi < 4; ++mi) {
        acc1[mi][ni] = __builtin_amdgcn_mfma_f32_16x16x32_bf16(af[mi], b1, acc1[mi][ni], 0, 0, 0);
        acc3[mi][ni] = __builtin_amdgcn_mfma_f32_16x16x32_bf16(af[mi], b3, acc3[mi][ni], 0, 0, 0);
      }
    }
    __builtin_amdgcn_s_setprio(0);
    // (5) counted-vmcnt barrier: only A(it+1) must land; B(it+2) stays in flight
    if (it < 31) {
      if (it < 30) asm volatile("s_waitcnt vmcnt(16) lgkmcnt(0)" ::: "memory");
      else         asm volatile("s_waitcnt vmcnt(0) lgkmcnt(0)" ::: "memory");
      __builtin_amdgcn_s_barrier();
      __builtin_amdgcn_sched_barrier(0);
    }
  }
  const int rb = wr * 64 + 4 * (lane >> 4), cb = wc * 32 + (lane & 15);
#pragma unroll
  for (int mi = 0; mi < 4; ++mi)
#pragma unroll
    for (int ni = 0; ni < 2; ++ni)
#pragma unroll
      for (int r = 0; r < 4; ++r) {
        float h1 = acc1[mi][ni][r], h3 = acc3[mi][ni][r];
        float gv = h1 / (1.f + __expf(-h1)) * h3;
        G[(size_t)(row0 + rb + mi * 16 + r) * Ff + n0 + cb + ni * 16] = f2bf(gv);
      }
}

// ---------- stage B fused: out[t] += w * (G@w2^T), K-split x2 ----------
// BM=BN=128, BK=32, 512 thr, same pipeline. 56 iters per split.
__global__ __launch_bounds__(512, 4) void ffn2_fused(
    const unsigned short* __restrict__ G, const float* __restrict__ w2,
    const int* __restrict__ ctrl, const int* __restrict__ rowmap,
    const float* __restrict__ roww, float* __restrict__ out) {
  __shared__ alignas(16) char sA[2][8192], sB[2][8192];
  int lin = (blockIdx.z * 128 + blockIdx.y) * 8 + blockIdx.x;  // 0..2047
  int xcd = lin & 7, idx = lin >> 3;               // idx 0..255
  int e = idx >> 5, sub = idx & 31;
  int mt = sub >> 1, ks = sub & 1;
  int bx = xcd;                                    // panel (e,bx) pinned to XCD
  const int off0 = ctrl[16 + e], off1 = ctrl[16 + e + 1];
  const int row0 = off0 + mt * 128;
  if (row0 >= off1) return;
  const int n0 = bx * 128;
  const int kb = ks * (Ff / 2);
  const int tid = threadIdx.x, lane = tid & 63, wv = tid >> 6;
  const int wr = wv >> 2, wc = wv & 3;             // wave tile 64x32
  const float* w2e = w2 + (size_t)e * Ff * Hh;
  f32x4 acc[4][2] = {};
  const int srow = wv * 16 + (lane >> 2);
  const int sgc = (lane & 3) ^ ((lane >> 3) & 3);
  const unsigned short* gA = G + (size_t)(row0 + srow) * Ff + kb + sgc * 8;
  const int bn = tid & 127, bkq = tid >> 7;
  const int posB = bkq ^ ((bn >> 1) & 3);
  const int wofB = bn * 64 + posB * 16;
  const float* pB = w2e + (size_t)(kb + bkq * 8) * Hh + n0 + bn;
  float r2[8];

  // ---- prologue ----
  gload_lds16(gA, sA[0] + wv * 1024);
#pragma unroll
  for (int i = 0; i < 8; ++i) r2[i] = pB[(size_t)i * Hh];
  {
    uint4 q;
    q.x = pkbf(r2[0], r2[1]); q.y = pkbf(r2[2], r2[3]);
    q.z = pkbf(r2[4], r2[5]); q.w = pkbf(r2[6], r2[7]);
    *(uint4*)(sB[0] + wofB) = q;
  }
#pragma unroll
  for (int i = 0; i < 8; ++i) r2[i] = pB[(size_t)(32 + i) * Hh];
  asm volatile("s_waitcnt vmcnt(8) lgkmcnt(0)" ::: "memory");
  __builtin_amdgcn_s_barrier();
  __builtin_amdgcn_sched_barrier(0);

  const int NT = 56;
  for (int it = 0; it < NT; ++it) {
    const int cur = it & 1;
    if (it < NT - 1) gload_lds16(gA + (size_t)(it + 1) * 32, sA[cur ^ 1] + wv * 1024);
    __builtin_amdgcn_sched_barrier(0);
    if (it < NT - 1) {
      uint4 q;
      q.x = pkbf(r2[0], r2[1]); q.y = pkbf(r2[2], r2[3]);
      q.z = pkbf(r2[4], r2[5]); q.w = pkbf(r2[6], r2[7]);
      *(uint4*)(sB[cur ^ 1] + wofB) = q;
    }
    if (it < NT - 2) {
      const float* p2 = pB + (size_t)(it + 2) * 32 * Hh;
#pragma unroll
      for (int i = 0; i < 8; ++i) r2[i] = p2[(size_t)i * Hh];
    }
    __builtin_amdgcn_sched_barrier(0);
    const int gc = lane >> 4;
    bf16x8 af[4];
#pragma unroll
    for (int mi = 0; mi < 4; ++mi)
      af[mi] = frg(sA[cur], wr * 64 + mi * 16 + (lane & 15), gc);
    __builtin_amdgcn_s_setprio(1);
#pragma unroll
    for (int ni = 0; ni < 2; ++ni) {
      bf16x8 b = frg(sB[cur], wc * 32 + ni * 16 + (lane & 15), gc);
#pragma unroll
      for (int mi = 0; mi < 4; ++mi)
        acc[mi][ni] = __builtin_amdgcn_mfma_f32_16x16x32_bf16(af[mi], b, acc[mi][ni], 0, 0, 0);
    }
    __builtin_amdgcn_s_setprio(0);
    if (it < NT - 1) {
      if (it < NT - 2) asm volatile("s_waitcnt vmcnt(8) lgkmcnt(0)" ::: "memory");
      else             asm volatile("s_waitcnt vmcnt(0) lgkmcnt(0)" ::: "memory");
      __builtin_amdgcn_s_barrier();
      __builtin_amdgcn_sched_barrier(0);
    }
  }
  const int rb = wr * 64 + 4 * (lane >> 4), cb = wc * 32 + (lane & 15);
#pragma unroll
  for (int mi = 0; mi < 4; ++mi)
#pragma unroll
    for (int r = 0; r < 4; ++r) {
      int grow = row0 + rb + mi * 16 + r;
      int t = rowmap[grow];
      if (t < 0) continue;
      float wgt = roww[grow];
#pragma unroll
      for (int ni = 0; ni < 2; ++ni)
        atomicAdd(&out[(size_t)t * Hh + n0 + cb + ni * 16], wgt * acc[mi][ni][r]);
    }
}

extern "C" void kernel_launch(void* const* d_in, const int* in_sizes, int n_in,
                              void* d_out, int out_size, void* d_ws, size_t ws_size,
                              hipStream_t stream) {
  const float* x  = (const float*)d_in[0];
  const float* gw = (const float*)d_in[1];
  const float* w1 = (const float*)d_in[2];
  const float* w3 = (const float*)d_in[3];
  const float* w2 = (const float*)d_in[4];
  float* out = (float*)d_out;
  float* logits = out + (size_t)Tt * Hh;
  char* ws = (char*)d_ws;
  int* ctrl = (int*)(ws + OFF_CTRL);
  int* tok_e = (int*)(ws + OFF_TOKE);
  float* tok_w = (float*)(ws + OFF_TOKW);
  int* rowmap = (int*)(ws + OFF_ROWMAP);
  float* roww = (float*)(ws + OFF_ROWW);
  unsigned short* Xg = (unsigned short*)(ws + OFF_XG);
  unsigned short* G  = (unsigned short*)(ws + OFF_G);

  hipMemsetAsync(ctrl, 0, 256, stream);
  hipMemsetAsync(out, 0, (size_t)Tt * Hh * sizeof(float), stream);
  router_kernel<<<Tt / 4, 256, 0, stream>>>(x, gw, logits, tok_e, tok_w, ctrl);
  offsets_kernel<<<1, 64, 0, stream>>>(ctrl);
  assign_kernel<<<8, 512, 0, stream>>>(ctrl, tok_e, tok_w, rowmap, roww);
  gather_kernel<<<ROWS_CAP, 128, 0, stream>>>(x, ctrl, rowmap, Xg);
  ffn13_fused<<<dim3(28, 128), 512, 0, stream>>>(Xg, w1, w3, ctrl, G);
  ffn2_fused<<<dim3(8, 128, 2), 512, 0, stream>>>(G, w2, ctrl, rowmap, roww, out);
}